// Round 10
// baseline (265.713 us; speedup 1.0000x reference)
//
#include <hip/hip_runtime.h>

#define DIM 64
#define NCLS 249
#define SCAN_CHUNK 1024
#define NCHUNK 192
#define PSHIFT 7
#define PSIZE 128
#define SBITS 17
#define SMASK ((1u << SBITS) - 1)
#define MAXP 1024   // max partitions (N <= 131072)

typedef unsigned int u32;
typedef unsigned short u16;
using bf16x8 = __attribute__((ext_vector_type(8))) short;
using f32x4  = __attribute__((ext_vector_type(4))) float;

__device__ __forceinline__ u16 f2bf(float f) {
    u32 u = __builtin_bit_cast(u32, f);
    u += 0x7FFFu + ((u >> 16) & 1u);   // round-to-nearest-even
    return (u16)(u >> 16);
}
__device__ __forceinline__ float bf_lo(u32 u) { return __builtin_bit_cast(float, u << 16); }
__device__ __forceinline__ float bf_hi(u32 u) { return __builtin_bit_cast(float, u & 0xFFFF0000u); }

// ---------------- fused: per-(chunk,part) edge counts + prep (x->bf16, B1, B2) ----------------
__global__ __launch_bounds__(256) void build_kernel(
    const int* __restrict__ dst, int E, int chunk_size, int nxp,
    int* __restrict__ bcnt,
    const float* __restrict__ x, u16* __restrict__ A1, int nx8,
    const float* __restrict__ W1l, const float* __restrict__ W1r, u16* __restrict__ B1,
    const float* __restrict__ W2l, const float* __restrict__ W2r, u16* __restrict__ B2)
{
    __shared__ int c[MAXP];
    int t = threadIdx.x;
    if (blockIdx.x < NCHUNK) {
        // histogram branch
        for (int i = t; i < nxp; i += 256) c[i] = 0;
        __syncthreads();
        int base = blockIdx.x * chunk_size;
        int end = min(base + chunk_size, E);
        for (int e = base + t; e < end; e += 256) {
            int d = __builtin_nontemporal_load(&dst[e]);
            atomicAdd(&c[d >> PSHIFT], 1);
        }
        __syncthreads();
        for (int i = t; i < nxp; i += 256) bcnt[i * NCHUNK + blockIdx.x] = c[i];
        return;
    }
    // prep branch
    int i = (blockIdx.x - NCHUNK) * 256 + t;
    if (i < nx8) {
        int node = i >> 3, seg = i & 7;
        const float4 v0 = *(const float4*)(x + (size_t)i * 8);
        const float4 v1 = *(const float4*)(x + (size_t)i * 8 + 4);
        uint4 o;
        o.x = (u32)f2bf(v0.x) | ((u32)f2bf(v0.y) << 16);
        o.y = (u32)f2bf(v0.z) | ((u32)f2bf(v0.w) << 16);
        o.z = (u32)f2bf(v1.x) | ((u32)f2bf(v1.y) << 16);
        o.w = (u32)f2bf(v1.z) | ((u32)f2bf(v1.w) << 16);
        *(uint4*)(A1 + (size_t)node * 128 + 64 + seg * 8) = o;
        return;
    }
    int j = i - nx8;
    if (j < 64 * 128) {
        int r = j >> 7, k = j & 127;
        B1[j] = f2bf(k < 64 ? W1l[r * 64 + k] : W1r[r * 64 + k - 64]);
        return;
    }
    j -= 64 * 128;
    if (j < 256 * 128) {
        int r = j >> 7, k = j & 127;
        float v = 0.f;
        if (r < NCLS) v = (k < 64) ? W2l[r * 64 + k] : W2r[r * 64 + k - 64];
        B2[j] = f2bf(v);
    }
}

// ---------------- scan level 1: per-1024-chunk sums ----------------
__global__ __launch_bounds__(256) void scan_block_sums(const int* __restrict__ cnt, int n,
                                                       int* __restrict__ bsum) {
    __shared__ int sdata[256];
    int b = blockIdx.x, t = threadIdx.x;
    int base = b * SCAN_CHUNK;
    int s = 0;
    for (int i = t; i < SCAN_CHUNK; i += 256) {
        int idx = base + i;
        s += (idx < n) ? cnt[idx] : 0;
    }
    sdata[t] = s;
    __syncthreads();
    for (int off = 128; off > 0; off >>= 1) {
        if (t < off) sdata[t] += sdata[t + off];
        __syncthreads();
    }
    if (t == 0) bsum[b] = sdata[0];
}

// ---------------- scan level 2: final, self-scanning raw bsum (nb <= 256) ----------------
__global__ __launch_bounds__(256) void scan_final_boff(const int* __restrict__ cnt, int n,
                                                       const int* __restrict__ bsum_raw, int nb,
                                                       int* __restrict__ boff, int total) {
    __shared__ int bpre[256];
    __shared__ int tsum[256];
    int b = blockIdx.x, t = threadIdx.x;
    // redundant in-block inclusive scan of raw block sums (147 entries)
    int bv = (t < nb) ? bsum_raw[t] : 0;
    bpre[t] = bv;
    __syncthreads();
    for (int off = 1; off < 256; off <<= 1) {
        int u = (t >= off) ? bpre[t - off] : 0;
        __syncthreads();
        bpre[t] += u;
        __syncthreads();
    }
    int block_base = (b == 0) ? 0 : bpre[b - 1];
    int base = b * SCAN_CHUNK + t * 4;
    int v[4];
    int s = 0;
#pragma unroll
    for (int i = 0; i < 4; ++i) {
        int id = base + i;
        v[i] = (id < n) ? cnt[id] : 0;
        s += v[i];
    }
    tsum[t] = s;
    __syncthreads();
    for (int off = 1; off < 256; off <<= 1) {
        int u = (t >= off) ? tsum[t - off] : 0;
        __syncthreads();
        tsum[t] += u;
        __syncthreads();
    }
    int run = tsum[t] - s + block_base;
#pragma unroll
    for (int i = 0; i < 4; ++i) {
        int id = base + i;
        if (id < n) boff[id] = run;
        run += v[i];
    }
    if (b == 0 && t == 0) boff[n] = total;
}

// ---------------- scatter packed edges into per-part buckets ----------------
__global__ __launch_bounds__(256) void bucket_scatter(const int* __restrict__ ei, int E,
                                                      int chunk_size, int nxp,
                                                      const int* __restrict__ boff,
                                                      u32* __restrict__ bucket) {
    __shared__ int cur[MAXP];
    int t = threadIdx.x;
    for (int i = t; i < nxp; i += 256) cur[i] = boff[i * NCHUNK + blockIdx.x];
    __syncthreads();
    int base = blockIdx.x * chunk_size;
    int end = min(base + chunk_size, E);
    for (int e = base + t; e < end; e += 256) {
        int s = __builtin_nontemporal_load(&ei[e]);
        int d = __builtin_nontemporal_load(&ei[E + e]);
        int pos = atomicAdd(&cur[d >> PSHIFT], 1);
        bucket[pos] = ((u32)(d & (PSIZE - 1)) << SBITS) | (u32)s;
    }
}

// ---------------- counting-sort each partition slice -> nbr + row_ptr ----------------
__global__ __launch_bounds__(256) void sort_bucket(const u32* __restrict__ bucket,
                                                   const int* __restrict__ boff,
                                                   int* __restrict__ nbr,
                                                   int* __restrict__ row_ptr,
                                                   int n, int E) {
    __shared__ int cnt[PSIZE];
    __shared__ int sc[PSIZE];
    __shared__ int cur[PSIZE];
    int t = threadIdx.x;
    int p = blockIdx.x;
    if (t < PSIZE) cnt[t] = 0;
    __syncthreads();
    int beg = boff[p * NCHUNK];
    int end = boff[(p + 1) * NCHUNK];   // sentinel covers last partition
    for (int i = beg + t; i < end; i += 256)
        atomicAdd(&cnt[bucket[i] >> SBITS], 1);
    __syncthreads();
    if (t < PSIZE) sc[t] = cnt[t];
    __syncthreads();
    for (int off = 1; off < PSIZE; off <<= 1) {
        int v = 0;
        if (t < PSIZE && t >= off) v = sc[t - off];
        __syncthreads();
        if (t < PSIZE) sc[t] += v;
        __syncthreads();
    }
    if (t < PSIZE) {
        int excl = beg + sc[t] - cnt[t];
        cur[t] = excl;
        int node = p * PSIZE + t;
        if (node < n) row_ptr[node] = excl;
    }
    if (p == 0 && t == 0) row_ptr[n] = E;
    __syncthreads();
    for (int i = beg + t; i < end; i += 256) {
        u32 pk = bucket[i];
        int pos = atomicAdd(&cur[pk >> SBITS], 1);
        nbr[pos] = (int)(pk & SMASK);
    }
}

// ---------------- fused gather-aggregate + MFMA GEMM ----------------
// A-tile left half (cols 0..63) built in-kernel by gathering neighbor rows of
// Asrc cols 64..127; right half staged from Asrc cols 64..127 directly.
template<int NT, bool RELU, bool OUT_BF16>
__global__ __launch_bounds__(256) void gemm_fused(
    const u16* __restrict__ A, const u16* __restrict__ B,
    const float* __restrict__ bias,
    const int* __restrict__ row_ptr, const int* __restrict__ nbr,
    float* __restrict__ outf, u16* __restrict__ outb,
    int n_nodes, int n_cols)
{
    constexpr int KC = (NT == 16) ? 2 : 1;
    constexpr int KW = 128 / KC;
    constexpr int RG = KW / 8;
    constexpr int NR = NT * 16;
    __shared__ uint4 smem[3072];          // 48 KB: A_lds[0..1024) | B_lds[1024..3072)
    uint4* A_lds = smem;
    uint4* B_lds = smem + 1024;

    const int t = threadIdx.x;
    const int node0 = blockIdx.x * 64;
    const int q = t & 7;

    // right half (source features, cols 64..127) from global
#pragma unroll
    for (int i = 0; i < 2; ++i) {
        int gl = t + 256 * i;              // 0..511
        int r = gl >> 3;                   // row 0..63
        int g = 8 + (gl & 7);              // granules 8..15
        uint4 v = make_uint4(0u, 0u, 0u, 0u);
        int node = node0 + r;
        if (node < n_nodes) v = *(const uint4*)(A + (size_t)node * 128 + g * 8);
        A_lds[r * 16 + (g ^ (r & 7))] = v;
    }

    // left half (cols 0..63): gather-aggregate neighbors (shfl-batched)
#pragma unroll
    for (int pass = 0; pass < 2; ++pass) {
        int nl = (t >> 3) + pass * 32;     // row 0..63
        int node = node0 + nl;
        float a0 = 0.f, a1 = 0.f, a2 = 0.f, a3 = 0.f,
              a4 = 0.f, a5 = 0.f, a6 = 0.f, a7 = 0.f;
        if (node < n_nodes) {
            int beg = row_ptr[node], end = row_ptr[node + 1];
            for (int j0 = beg; j0 < end; j0 += 8) {
                int myj = j0 + q;
                int smine = (myj < end) ? nbr[myj] : 0;
                int cnt = min(8, end - j0);
#pragma unroll 4
                for (int k = 0; k < cnt; ++k) {
                    int s = __shfl(smine, k, 8);
                    uint4 v = *(const uint4*)(A + (size_t)s * 128 + 64 + q * 8);
                    a0 += bf_lo(v.x); a1 += bf_hi(v.x);
                    a2 += bf_lo(v.y); a3 += bf_hi(v.y);
                    a4 += bf_lo(v.z); a5 += bf_hi(v.z);
                    a6 += bf_lo(v.w); a7 += bf_hi(v.w);
                }
            }
        }
        uint4 o;
        o.x = (u32)f2bf(a0) | ((u32)f2bf(a1) << 16);
        o.y = (u32)f2bf(a2) | ((u32)f2bf(a3) << 16);
        o.z = (u32)f2bf(a4) | ((u32)f2bf(a5) << 16);
        o.w = (u32)f2bf(a6) | ((u32)f2bf(a7) << 16);
        A_lds[nl * 16 + (q ^ (nl & 7))] = o;
    }

    const int w  = t >> 6;
    const int l  = t & 63;
    const int lm = l & 15;
    const int lg = l >> 4;
    const int arow = w * 16 + lm;
    const int asw  = arow & 7;

    f32x4 acc[NT];
#pragma unroll
    for (int n = 0; n < NT; ++n) acc[n] = f32x4{0.f, 0.f, 0.f, 0.f};

#pragma unroll
    for (int kc = 0; kc < KC; ++kc) {
        __syncthreads();
#pragma unroll
        for (int i = 0; i < (NR * RG) / 256; ++i) {
            int gl = t + 256 * i;
            int r = gl / RG, g = gl % RG;
            uint4 v = *(const uint4*)(B + (size_t)r * 128 + kc * KW + g * 8);
            B_lds[r * RG + (g ^ (r & 7))] = v;
        }
        __syncthreads();
#pragma unroll
        for (int ks = 0; ks < KW / 32; ++ks) {
            int ag = lg + (kc * (KW / 32) + ks) * 4;
            bf16x8 af = __builtin_bit_cast(bf16x8, A_lds[arow * 16 + (ag ^ asw)]);
#pragma unroll
            for (int n = 0; n < NT; ++n) {
                int brow = n * 16 + lm;
                int bg = lg + ks * 4;
                bf16x8 bf = __builtin_bit_cast(bf16x8, B_lds[brow * RG + (bg ^ (brow & 7))]);
                acc[n] = __builtin_amdgcn_mfma_f32_16x16x32_bf16(af, bf, acc[n], 0, 0, 0);
            }
        }
    }

    if (OUT_BF16) {
        // bf16 path (layer 1): D col = lane&15 (+tile*16), row = (lane>>4)*4+reg (+wave*16)
        const int rbase = w * 16 + lg * 4;
#pragma unroll
        for (int n = 0; n < NT; ++n) {
            int c = n * 16 + lm;
            float bv = (c < n_cols) ? bias[c] : 0.f;
#pragma unroll
            for (int r = 0; r < 4; ++r) {
                int node = node0 + rbase + r;
                if (node < n_nodes && c < n_cols) {
                    float v = acc[n][r] + bv;
                    if (RELU) v = fmaxf(v, 0.f);
                    outb[(size_t)node * 128 + 64 + c] = f2bf(v);
                }
            }
        }
    } else {
        // f32 path (layer 2): per-wave LDS transpose, coalesced row stores
        float bc[NT];
#pragma unroll
        for (int n = 0; n < NT; ++n) {
            int c = n * 16 + lm;
            bc[n] = (c < n_cols) ? bias[c] : 0.f;
        }
        float* S = reinterpret_cast<float*>(smem);
        __syncthreads();   // all waves done reading A_lds/B_lds
#pragma unroll
        for (int rc = 0; rc < 2; ++rc) {
            if (rc) __syncthreads();
            if ((lg >> 1) == rc) {
                int lrow = (lg & 1) * 4;
                float* Sw = S + ((size_t)w * 8 + lrow) * 264;
#pragma unroll
                for (int n = 0; n < NT; ++n) {
#pragma unroll
                    for (int r = 0; r < 4; ++r) {
                        float v = acc[n][r] + bc[n];
                        if (RELU) v = fmaxf(v, 0.f);
                        Sw[r * 264 + n * 16 + lm] = v;
                    }
                }
            }
            __syncthreads();
            const float* Sw = S + (size_t)w * 8 * 264;
#pragma unroll
            for (int row8 = 0; row8 < 8; ++row8) {
                int node = node0 + w * 16 + rc * 8 + row8;   // wave-uniform
                if (node >= n_nodes) continue;
                float* orow = outf + (size_t)node * (size_t)n_cols;
#pragma unroll
                for (int k = 0; k < 4; ++k) {
                    int c = k * 64 + l;
                    if (c < n_cols) orow[c] = Sw[row8 * 264 + c];
                }
            }
        }
    }
}

extern "C" void kernel_launch(void* const* d_in, const int* in_sizes, int n_in,
                              void* d_out, int out_size, void* d_ws, size_t ws_size,
                              hipStream_t stream) {
    const float* x   = (const float*)d_in[0];
    const int*   ei  = (const int*)d_in[1];
    const float* W1l = (const float*)d_in[2];
    const float* b1  = (const float*)d_in[3];
    const float* W1r = (const float*)d_in[4];
    const float* W2l = (const float*)d_in[5];
    const float* b2  = (const float*)d_in[6];
    const float* W2r = (const float*)d_in[7];
    float* out = (float*)d_out;

    const int N = in_sizes[0] / DIM;     // 100000  (< 2^17, required by packing)
    const int E = in_sizes[1] / 2;       // 1600000
    const int NPAD = ((N + 63) / 64) * 64;
    const int NXP = (N + PSIZE - 1) / PSIZE;          // 782 partitions
    const int NSC = NXP * NCHUNK;                     // 150144 scan entries
    const int NB2 = (NSC + SCAN_CHUNK - 1) / SCAN_CHUNK;   // 147 (<=256 required)

    // workspace layout
    char* wp = (char*)d_ws;
    u16* A1 = (u16*)wp;                 wp += (size_t)NPAD * 128 * 2;
    u16* A2 = (u16*)wp;                 wp += (size_t)NPAD * 128 * 2;
    u16* B1 = (u16*)wp;                 wp += 64 * 128 * 2;
    u16* B2 = (u16*)wp;                 wp += 256 * 128 * 2;
    int* bcnt = (int*)wp;               wp += (size_t)NSC * 4;
    int* boff = (int*)wp;               wp += (size_t)(NSC + 1) * 4;
    int* bsum = (int*)wp;               wp += 1024 * 4;
    int* row_ptr = (int*)wp;            wp += (size_t)(N + 1) * 4;
    u32* bucket = (u32*)wp;             wp += (size_t)E * 4;
    int* nbr = (int*)wp;                wp += (size_t)E * 4;

    const int chunk_size = (E + NCHUNK - 1) / NCHUNK;
    const int nx8 = N * 8;
    const int prep_items = nx8 + 64 * 128 + 256 * 128;
    const int prep_blocks = (prep_items + 255) / 256;

    // ---- fused histogram + prep ----
    build_kernel<<<NCHUNK + prep_blocks, 256, 0, stream>>>(
        ei + E, E, chunk_size, NXP, bcnt, x, A1, nx8, W1l, W1r, B1, W2l, W2r, B2);

    // ---- 2-launch scan ----
    scan_block_sums<<<NB2, 256, 0, stream>>>(bcnt, NSC, bsum);
    scan_final_boff<<<NB2, 256, 0, stream>>>(bcnt, NSC, bsum, NB2, boff, E);

    // ---- scatter + per-partition counting sort ----
    bucket_scatter<<<NCHUNK, 256, 0, stream>>>(ei, E, chunk_size, NXP, boff, bucket);
    sort_bucket<<<NXP, 256, 0, stream>>>(bucket, boff, nbr, row_ptr, N, E);

    const int gemm_blocks = NPAD / 64;

    // ---- layer 1 (fused aggregate + GEMM) ----
    gemm_fused<4, true, true><<<gemm_blocks, 256, 0, stream>>>(
        A1, B1, b1, row_ptr, nbr, nullptr, A2, N, 64);

    // ---- layer 2 (fused aggregate + GEMM) ----
    gemm_fused<16, false, false><<<gemm_blocks, 256, 0, stream>>>(
        A2, B2, b2, row_ptr, nbr, out, nullptr, N, NCLS);
}

// Round 11
// 208.008 us; speedup vs baseline: 1.2774x; 1.2774x over previous
//
#include <hip/hip_runtime.h>

#define DIM 64
#define NCLS 249
#define SCAN_CHUNK 1024
#define NCHUNK 192
#define PSHIFT 7
#define PSIZE 128
#define SBITS 17
#define SMASK ((1u << SBITS) - 1)
#define MAXP 1024   // max partitions (N <= 131072)
#define SLCAP 4096  // LDS slice capacity (edges); mean 2048, 45 sigma headroom

typedef unsigned int u32;
typedef unsigned short u16;
using bf16x8 = __attribute__((ext_vector_type(8))) short;
using f32x4  = __attribute__((ext_vector_type(4))) float;

__device__ __forceinline__ u16 f2bf(float f) {
    u32 u = __builtin_bit_cast(u32, f);
    u += 0x7FFFu + ((u >> 16) & 1u);   // round-to-nearest-even
    return (u16)(u >> 16);
}
__device__ __forceinline__ float bf_lo(u32 u) { return __builtin_bit_cast(float, u << 16); }
__device__ __forceinline__ float bf_hi(u32 u) { return __builtin_bit_cast(float, u & 0xFFFF0000u); }

// ---------------- fused: per-(chunk,part) edge counts + prep (x->bf16, B1, B2) ----------------
__global__ __launch_bounds__(256) void build_kernel(
    const int* __restrict__ dst, int E, int chunk_size, int nxp,
    int* __restrict__ bcnt,
    const float* __restrict__ x, u16* __restrict__ A1, int nx8,
    const float* __restrict__ W1l, const float* __restrict__ W1r, u16* __restrict__ B1,
    const float* __restrict__ W2l, const float* __restrict__ W2r, u16* __restrict__ B2)
{
    __shared__ int c[MAXP];
    int t = threadIdx.x;
    if (blockIdx.x < NCHUNK) {
        for (int i = t; i < nxp; i += 256) c[i] = 0;
        __syncthreads();
        int base = blockIdx.x * chunk_size;
        int end = min(base + chunk_size, E);
        for (int e = base + t; e < end; e += 256) {
            int d = __builtin_nontemporal_load(&dst[e]);
            atomicAdd(&c[d >> PSHIFT], 1);
        }
        __syncthreads();
        for (int i = t; i < nxp; i += 256) bcnt[i * NCHUNK + blockIdx.x] = c[i];
        return;
    }
    int i = (blockIdx.x - NCHUNK) * 256 + t;
    if (i < nx8) {
        int node = i >> 3, seg = i & 7;
        const float4 v0 = *(const float4*)(x + (size_t)i * 8);
        const float4 v1 = *(const float4*)(x + (size_t)i * 8 + 4);
        uint4 o;
        o.x = (u32)f2bf(v0.x) | ((u32)f2bf(v0.y) << 16);
        o.y = (u32)f2bf(v0.z) | ((u32)f2bf(v0.w) << 16);
        o.z = (u32)f2bf(v1.x) | ((u32)f2bf(v1.y) << 16);
        o.w = (u32)f2bf(v1.z) | ((u32)f2bf(v1.w) << 16);
        *(uint4*)(A1 + (size_t)node * 128 + 64 + seg * 8) = o;
        return;
    }
    int j = i - nx8;
    if (j < 64 * 128) {
        int r = j >> 7, k = j & 127;
        B1[j] = f2bf(k < 64 ? W1l[r * 64 + k] : W1r[r * 64 + k - 64]);
        return;
    }
    j -= 64 * 128;
    if (j < 256 * 128) {
        int r = j >> 7, k = j & 127;
        float v = 0.f;
        if (r < NCLS) v = (k < 64) ? W2l[r * 64 + k] : W2r[r * 64 + k - 64];
        B2[j] = f2bf(v);
    }
}

// ---------------- scan level 1: per-1024-chunk sums ----------------
__global__ __launch_bounds__(256) void scan_block_sums(const int* __restrict__ cnt, int n,
                                                       int* __restrict__ bsum) {
    __shared__ int sdata[256];
    int b = blockIdx.x, t = threadIdx.x;
    int base = b * SCAN_CHUNK;
    int s = 0;
    for (int i = t; i < SCAN_CHUNK; i += 256) {
        int idx = base + i;
        s += (idx < n) ? cnt[idx] : 0;
    }
    sdata[t] = s;
    __syncthreads();
    for (int off = 128; off > 0; off >>= 1) {
        if (t < off) sdata[t] += sdata[t + off];
        __syncthreads();
    }
    if (t == 0) bsum[b] = sdata[0];
}

// ---------------- scan level 2: final, self-scanning raw bsum (nb <= 256) ----------------
__global__ __launch_bounds__(256) void scan_final_boff(const int* __restrict__ cnt, int n,
                                                       const int* __restrict__ bsum_raw, int nb,
                                                       int* __restrict__ boff, int total) {
    __shared__ int bpre[256];
    __shared__ int tsum[256];
    int b = blockIdx.x, t = threadIdx.x;
    int bv = (t < nb) ? bsum_raw[t] : 0;
    bpre[t] = bv;
    __syncthreads();
    for (int off = 1; off < 256; off <<= 1) {
        int u = (t >= off) ? bpre[t - off] : 0;
        __syncthreads();
        bpre[t] += u;
        __syncthreads();
    }
    int block_base = (b == 0) ? 0 : bpre[b - 1];
    int base = b * SCAN_CHUNK + t * 4;
    int v[4];
    int s = 0;
#pragma unroll
    for (int i = 0; i < 4; ++i) {
        int id = base + i;
        v[i] = (id < n) ? cnt[id] : 0;
        s += v[i];
    }
    tsum[t] = s;
    __syncthreads();
    for (int off = 1; off < 256; off <<= 1) {
        int u = (t >= off) ? tsum[t - off] : 0;
        __syncthreads();
        tsum[t] += u;
        __syncthreads();
    }
    int run = tsum[t] - s + block_base;
#pragma unroll
    for (int i = 0; i < 4; ++i) {
        int id = base + i;
        if (id < n) boff[id] = run;
        run += v[i];
    }
    if (b == 0 && t == 0) boff[n] = total;
}

// ---------------- scatter packed edges into per-part buckets ----------------
__global__ __launch_bounds__(256) void bucket_scatter(const int* __restrict__ ei, int E,
                                                      int chunk_size, int nxp,
                                                      const int* __restrict__ boff,
                                                      u32* __restrict__ bucket) {
    __shared__ int cur[MAXP];
    int t = threadIdx.x;
    for (int i = t; i < nxp; i += 256) cur[i] = boff[i * NCHUNK + blockIdx.x];
    __syncthreads();
    int base = blockIdx.x * chunk_size;
    int end = min(base + chunk_size, E);
    for (int e = base + t; e < end; e += 256) {
        int s = __builtin_nontemporal_load(&ei[e]);
        int d = __builtin_nontemporal_load(&ei[E + e]);
        int pos = atomicAdd(&cur[d >> PSHIFT], 1);
        bucket[pos] = ((u32)(d & (PSIZE - 1)) << SBITS) | (u32)s;
    }
}

// ---------------- counting sort + layer-1 aggregate (per partition) ----------------
// Sorts partition slice -> nbr + row_ptr (for layer 2), keeps sorted srcs in LDS,
// then gathers/aggregates this partition's 128 nodes into A1 cols 0..63.
__global__ __launch_bounds__(256) void sort_pull1(const u32* __restrict__ bucket,
                                                  const int* __restrict__ boff,
                                                  int* __restrict__ nbr,
                                                  int* __restrict__ row_ptr,
                                                  const u16* __restrict__ Asrc,
                                                  u16* __restrict__ Adst,
                                                  int n, int E) {
    __shared__ int cnt[PSIZE];
    __shared__ int sc[PSIZE];
    __shared__ int cur[PSIZE];
    __shared__ int sl[SLCAP];   // 16 KB sorted-src slice
    int t = threadIdx.x;
    int p = blockIdx.x;
    if (t < PSIZE) cnt[t] = 0;
    __syncthreads();
    int beg = boff[p * NCHUNK];
    int end = boff[(p + 1) * NCHUNK];   // sentinel covers last partition
    int len = end - beg;
    for (int i = beg + t; i < end; i += 256)
        atomicAdd(&cnt[bucket[i] >> SBITS], 1);
    __syncthreads();
    if (t < PSIZE) sc[t] = cnt[t];
    __syncthreads();
    for (int off = 1; off < PSIZE; off <<= 1) {
        int v = 0;
        if (t < PSIZE && t >= off) v = sc[t - off];
        __syncthreads();
        if (t < PSIZE) sc[t] += v;
        __syncthreads();
    }
    if (t < PSIZE) {
        int excl = beg + sc[t] - cnt[t];
        cur[t] = excl;
        int node = p * PSIZE + t;
        if (node < n) row_ptr[node] = excl;
    }
    if (p == 0 && t == 0) row_ptr[n] = E;
    __syncthreads();
    const bool fits = (len <= SLCAP);
    for (int i = beg + t; i < end; i += 256) {
        u32 pk = bucket[i];
        int s = (int)(pk & SMASK);
        int pos = atomicAdd(&cur[pk >> SBITS], 1);
        nbr[pos] = s;                       // global copy for layer-2 pull
        if (fits) sl[pos - beg] = s;        // LDS copy for the gather below
    }
    __syncthreads();
    // gather-aggregate: 4 passes x 32 node-groups x 8 lanes
    int q = t & 7;
#pragma unroll
    for (int pass = 0; pass < 4; ++pass) {
        int nl = pass * 32 + (t >> 3);
        int node = p * PSIZE + nl;
        if (node >= n) continue;
        int lbeg = sc[nl] - cnt[nl];
        int lend = sc[nl];
        float a0 = 0.f, a1 = 0.f, a2 = 0.f, a3 = 0.f,
              a4 = 0.f, a5 = 0.f, a6 = 0.f, a7 = 0.f;
        for (int j = lbeg; j < lend; ++j) {
            int s = fits ? sl[j] : nbr[beg + j];
            uint4 v = *(const uint4*)(Asrc + (size_t)s * 128 + 64 + q * 8);
            a0 += bf_lo(v.x); a1 += bf_hi(v.x);
            a2 += bf_lo(v.y); a3 += bf_hi(v.y);
            a4 += bf_lo(v.z); a5 += bf_hi(v.z);
            a6 += bf_lo(v.w); a7 += bf_hi(v.w);
        }
        uint4 o;
        o.x = (u32)f2bf(a0) | ((u32)f2bf(a1) << 16);
        o.y = (u32)f2bf(a2) | ((u32)f2bf(a3) << 16);
        o.z = (u32)f2bf(a4) | ((u32)f2bf(a5) << 16);
        o.w = (u32)f2bf(a6) | ((u32)f2bf(a7) << 16);
        *(uint4*)(Adst + (size_t)node * 128 + q * 8) = o;
    }
}

// ---------------- pull aggregation: shuffle-shared nbr, 8-edge batches ----------------
__global__ __launch_bounds__(256) void pull_bf16(const u16* __restrict__ Asrc,
                                                 const int* __restrict__ row_ptr,
                                                 const int* __restrict__ nbr,
                                                 u16* __restrict__ Adst, int n) {
    int tid = blockIdx.x * 256 + threadIdx.x;
    int node = tid >> 3;
    int q = tid & 7;
    if (node >= n) return;
    int beg = row_ptr[node], end = row_ptr[node + 1];
    float a0 = 0.f, a1 = 0.f, a2 = 0.f, a3 = 0.f, a4 = 0.f, a5 = 0.f, a6 = 0.f, a7 = 0.f;
    for (int j0 = beg; j0 < end; j0 += 8) {
        int myj = j0 + q;
        int smine = (myj < end) ? nbr[myj] : 0;
        int cnt = min(8, end - j0);
#pragma unroll 4
        for (int k = 0; k < cnt; ++k) {
            int s = __shfl(smine, k, 8);
            uint4 v = *(const uint4*)(Asrc + (size_t)s * 128 + 64 + q * 8);
            a0 += bf_lo(v.x); a1 += bf_hi(v.x);
            a2 += bf_lo(v.y); a3 += bf_hi(v.y);
            a4 += bf_lo(v.z); a5 += bf_hi(v.z);
            a6 += bf_lo(v.w); a7 += bf_hi(v.w);
        }
    }
    uint4 o;
    o.x = (u32)f2bf(a0) | ((u32)f2bf(a1) << 16);
    o.y = (u32)f2bf(a2) | ((u32)f2bf(a3) << 16);
    o.z = (u32)f2bf(a4) | ((u32)f2bf(a5) << 16);
    o.w = (u32)f2bf(a6) | ((u32)f2bf(a7) << 16);
    *(uint4*)(Adst + (size_t)node * 128 + q * 8) = o;
}

// ---------------- MFMA GEMM: [64 nodes] x [NT*16 cols], K=128 ----------------
// f32 output path: LDS-transpose epilogue -> coalesced row-major stores
template<int NT, bool RELU, bool OUT_BF16>
__global__ __launch_bounds__(256) void gemm_kernel(
    const u16* __restrict__ A, const u16* __restrict__ B,
    const float* __restrict__ bias,
    float* __restrict__ outf, u16* __restrict__ outb,
    int n_nodes, int n_cols)
{
    constexpr int KC = (NT == 16) ? 2 : 1;
    constexpr int KW = 128 / KC;
    constexpr int RG = KW / 8;
    constexpr int NR = NT * 16;
    __shared__ uint4 smem[3072];          // 48 KB: A_lds[0..1024) | B_lds[1024..3072)
    uint4* A_lds = smem;
    uint4* B_lds = smem + 1024;

    const int t = threadIdx.x;
    const int node0 = blockIdx.x * 64;

#pragma unroll
    for (int i = 0; i < 4; ++i) {
        int gl = t + 256 * i;
        int r = gl >> 4, g = gl & 15;
        uint4 v = make_uint4(0u, 0u, 0u, 0u);
        int node = node0 + r;
        if (node < n_nodes) v = *(const uint4*)(A + (size_t)node * 128 + g * 8);
        A_lds[r * 16 + (g ^ (r & 7))] = v;
    }

    const int w  = t >> 6;
    const int l  = t & 63;
    const int lm = l & 15;
    const int lg = l >> 4;
    const int arow = w * 16 + lm;
    const int asw  = arow & 7;

    f32x4 acc[NT];
#pragma unroll
    for (int n = 0; n < NT; ++n) acc[n] = f32x4{0.f, 0.f, 0.f, 0.f};

#pragma unroll
    for (int kc = 0; kc < KC; ++kc) {
        __syncthreads();
#pragma unroll
        for (int i = 0; i < (NR * RG) / 256; ++i) {
            int gl = t + 256 * i;
            int r = gl / RG, g = gl % RG;
            uint4 v = *(const uint4*)(B + (size_t)r * 128 + kc * KW + g * 8);
            B_lds[r * RG + (g ^ (r & 7))] = v;
        }
        __syncthreads();
#pragma unroll
        for (int ks = 0; ks < KW / 32; ++ks) {
            int ag = lg + (kc * (KW / 32) + ks) * 4;
            bf16x8 af = __builtin_bit_cast(bf16x8, A_lds[arow * 16 + (ag ^ asw)]);
#pragma unroll
            for (int n = 0; n < NT; ++n) {
                int brow = n * 16 + lm;
                int bg = lg + ks * 4;
                bf16x8 bf = __builtin_bit_cast(bf16x8, B_lds[brow * RG + (bg ^ (brow & 7))]);
                acc[n] = __builtin_amdgcn_mfma_f32_16x16x32_bf16(af, bf, acc[n], 0, 0, 0);
            }
        }
    }

    if (OUT_BF16) {
        const int rbase = w * 16 + lg * 4;
#pragma unroll
        for (int n = 0; n < NT; ++n) {
            int c = n * 16 + lm;
            float bv = (c < n_cols) ? bias[c] : 0.f;
#pragma unroll
            for (int r = 0; r < 4; ++r) {
                int node = node0 + rbase + r;
                if (node < n_nodes && c < n_cols) {
                    float v = acc[n][r] + bv;
                    if (RELU) v = fmaxf(v, 0.f);
                    outb[(size_t)node * 128 + 64 + c] = f2bf(v);
                }
            }
        }
    } else {
        float bc[NT];
#pragma unroll
        for (int n = 0; n < NT; ++n) {
            int c = n * 16 + lm;
            bc[n] = (c < n_cols) ? bias[c] : 0.f;
        }
        float* S = reinterpret_cast<float*>(smem);
        __syncthreads();
#pragma unroll
        for (int rc = 0; rc < 2; ++rc) {
            if (rc) __syncthreads();
            if ((lg >> 1) == rc) {
                int lrow = (lg & 1) * 4;
                float* Sw = S + ((size_t)w * 8 + lrow) * 264;
#pragma unroll
                for (int n = 0; n < NT; ++n) {
#pragma unroll
                    for (int r = 0; r < 4; ++r) {
                        float v = acc[n][r] + bc[n];
                        if (RELU) v = fmaxf(v, 0.f);
                        Sw[r * 264 + n * 16 + lm] = v;
                    }
                }
            }
            __syncthreads();
            const float* Sw = S + (size_t)w * 8 * 264;
#pragma unroll
            for (int row8 = 0; row8 < 8; ++row8) {
                int node = node0 + w * 16 + rc * 8 + row8;   // wave-uniform
                if (node >= n_nodes) continue;
                float* orow = outf + (size_t)node * (size_t)n_cols;
#pragma unroll
                for (int k = 0; k < 4; ++k) {
                    int c = k * 64 + l;
                    if (c < n_cols) orow[c] = Sw[row8 * 264 + c];
                }
            }
        }
    }
}

extern "C" void kernel_launch(void* const* d_in, const int* in_sizes, int n_in,
                              void* d_out, int out_size, void* d_ws, size_t ws_size,
                              hipStream_t stream) {
    const float* x   = (const float*)d_in[0];
    const int*   ei  = (const int*)d_in[1];
    const float* W1l = (const float*)d_in[2];
    const float* b1  = (const float*)d_in[3];
    const float* W1r = (const float*)d_in[4];
    const float* W2l = (const float*)d_in[5];
    const float* b2  = (const float*)d_in[6];
    const float* W2r = (const float*)d_in[7];
    float* out = (float*)d_out;

    const int N = in_sizes[0] / DIM;     // 100000  (< 2^17, required by packing)
    const int E = in_sizes[1] / 2;       // 1600000
    const int NPAD = ((N + 63) / 64) * 64;
    const int NXP = (N + PSIZE - 1) / PSIZE;          // 782 partitions
    const int NSC = NXP * NCHUNK;                     // 150144 scan entries
    const int NB2 = (NSC + SCAN_CHUNK - 1) / SCAN_CHUNK;   // 147 (<=256 required)

    // workspace layout
    char* wp = (char*)d_ws;
    u16* A1 = (u16*)wp;                 wp += (size_t)NPAD * 128 * 2;
    u16* A2 = (u16*)wp;                 wp += (size_t)NPAD * 128 * 2;
    u16* B1 = (u16*)wp;                 wp += 64 * 128 * 2;
    u16* B2 = (u16*)wp;                 wp += 256 * 128 * 2;
    int* bcnt = (int*)wp;               wp += (size_t)NSC * 4;
    int* boff = (int*)wp;               wp += (size_t)(NSC + 1) * 4;
    int* bsum = (int*)wp;               wp += 1024 * 4;
    int* row_ptr = (int*)wp;            wp += (size_t)(N + 1) * 4;
    u32* bucket = (u32*)wp;             wp += (size_t)E * 4;
    int* nbr = (int*)wp;                wp += (size_t)E * 4;

    const int chunk_size = (E + NCHUNK - 1) / NCHUNK;
    const int nx8 = N * 8;
    const int prep_items = nx8 + 64 * 128 + 256 * 128;
    const int prep_blocks = (prep_items + 255) / 256;

    // ---- fused histogram + prep ----
    build_kernel<<<NCHUNK + prep_blocks, 256, 0, stream>>>(
        ei + E, E, chunk_size, NXP, bcnt, x, A1, nx8, W1l, W1r, B1, W2l, W2r, B2);

    // ---- 2-launch scan ----
    scan_block_sums<<<NB2, 256, 0, stream>>>(bcnt, NSC, bsum);
    scan_final_boff<<<NB2, 256, 0, stream>>>(bcnt, NSC, bsum, NB2, boff, E);

    // ---- scatter + fused sort/layer-1 aggregate ----
    bucket_scatter<<<NCHUNK, 256, 0, stream>>>(ei, E, chunk_size, NXP, boff, bucket);
    sort_pull1<<<NXP, 256, 0, stream>>>(bucket, boff, nbr, row_ptr, A1, A1, N, E);

    const int gemm_blocks = NPAD / 64;

    // ---- layer 1 GEMM ----
    gemm_kernel<4, true, true><<<gemm_blocks, 256, 0, stream>>>(A1, B1, b1, nullptr, A2, N, 64);

    // ---- layer 2 (pull at full occupancy, then GEMM) ----
    pull_bf16<<<(nx8 + 255) / 256, 256, 0, stream>>>(A2, row_ptr, nbr, A2, N);
    gemm_kernel<16, false, false><<<gemm_blocks, 256, 0, stream>>>(A2, B2, b2, out, nullptr, N, NCLS);
}

// Round 12
// 197.351 us; speedup vs baseline: 1.3464x; 1.0540x over previous
//
#include <hip/hip_runtime.h>

#define DIM 64
#define NCLS 249
#define SCAN_CHUNK 1024
#define NCHUNK 192
#define PSHIFT 7
#define PSIZE 128
#define SBITS 17
#define SMASK ((1u << SBITS) - 1)
#define MAXP 1024   // max partitions (N <= 131072)

typedef unsigned int u32;
typedef unsigned short u16;
using bf16x8 = __attribute__((ext_vector_type(8))) short;
using f32x4  = __attribute__((ext_vector_type(4))) float;

__device__ __forceinline__ u16 f2bf(float f) {
    u32 u = __builtin_bit_cast(u32, f);
    u += 0x7FFFu + ((u >> 16) & 1u);   // round-to-nearest-even
    return (u16)(u >> 16);
}
__device__ __forceinline__ float bf_lo(u32 u) { return __builtin_bit_cast(float, u << 16); }
__device__ __forceinline__ float bf_hi(u32 u) { return __builtin_bit_cast(float, u & 0xFFFF0000u); }

// ---------------- fused: per-(chunk,part) edge counts + prep (x->bf16, B1, B2) ----------------
__global__ __launch_bounds__(256) void build_kernel(
    const int* __restrict__ dst, int E, int chunk_size, int nxp,
    int* __restrict__ bcnt,
    const float* __restrict__ x, u16* __restrict__ A1, int nx8,
    const float* __restrict__ W1l, const float* __restrict__ W1r, u16* __restrict__ B1,
    const float* __restrict__ W2l, const float* __restrict__ W2r, u16* __restrict__ B2)
{
    __shared__ int c[MAXP];
    int t = threadIdx.x;
    if (blockIdx.x < NCHUNK) {
        for (int i = t; i < nxp; i += 256) c[i] = 0;
        __syncthreads();
        int base = blockIdx.x * chunk_size;
        int end = min(base + chunk_size, E);
        for (int e = base + t; e < end; e += 256) {
            int d = __builtin_nontemporal_load(&dst[e]);
            atomicAdd(&c[d >> PSHIFT], 1);
        }
        __syncthreads();
        for (int i = t; i < nxp; i += 256) bcnt[i * NCHUNK + blockIdx.x] = c[i];
        return;
    }
    int i = (blockIdx.x - NCHUNK) * 256 + t;
    if (i < nx8) {
        int node = i >> 3, seg = i & 7;
        const float4 v0 = *(const float4*)(x + (size_t)i * 8);
        const float4 v1 = *(const float4*)(x + (size_t)i * 8 + 4);
        uint4 o;
        o.x = (u32)f2bf(v0.x) | ((u32)f2bf(v0.y) << 16);
        o.y = (u32)f2bf(v0.z) | ((u32)f2bf(v0.w) << 16);
        o.z = (u32)f2bf(v1.x) | ((u32)f2bf(v1.y) << 16);
        o.w = (u32)f2bf(v1.z) | ((u32)f2bf(v1.w) << 16);
        *(uint4*)(A1 + (size_t)node * 128 + 64 + seg * 8) = o;
        return;
    }
    int j = i - nx8;
    if (j < 64 * 128) {
        int r = j >> 7, k = j & 127;
        B1[j] = f2bf(k < 64 ? W1l[r * 64 + k] : W1r[r * 64 + k - 64]);
        return;
    }
    j -= 64 * 128;
    if (j < 256 * 128) {
        int r = j >> 7, k = j & 127;
        float v = 0.f;
        if (r < NCLS) v = (k < 64) ? W2l[r * 64 + k] : W2r[r * 64 + k - 64];
        B2[j] = f2bf(v);
    }
}

// ---------------- scan level 1: per-1024-chunk sums ----------------
__global__ __launch_bounds__(256) void scan_block_sums(const int* __restrict__ cnt, int n,
                                                       int* __restrict__ bsum) {
    __shared__ int sdata[256];
    int b = blockIdx.x, t = threadIdx.x;
    int base = b * SCAN_CHUNK;
    int s = 0;
    for (int i = t; i < SCAN_CHUNK; i += 256) {
        int idx = base + i;
        s += (idx < n) ? cnt[idx] : 0;
    }
    sdata[t] = s;
    __syncthreads();
    for (int off = 128; off > 0; off >>= 1) {
        if (t < off) sdata[t] += sdata[t + off];
        __syncthreads();
    }
    if (t == 0) bsum[b] = sdata[0];
}

// ---------------- scan level 2: final, self-scanning raw bsum (nb <= 256) ----------------
__global__ __launch_bounds__(256) void scan_final_boff(const int* __restrict__ cnt, int n,
                                                       const int* __restrict__ bsum_raw, int nb,
                                                       int* __restrict__ boff, int total) {
    __shared__ int bpre[256];
    __shared__ int tsum[256];
    int b = blockIdx.x, t = threadIdx.x;
    int bv = (t < nb) ? bsum_raw[t] : 0;
    bpre[t] = bv;
    __syncthreads();
    for (int off = 1; off < 256; off <<= 1) {
        int u = (t >= off) ? bpre[t - off] : 0;
        __syncthreads();
        bpre[t] += u;
        __syncthreads();
    }
    int block_base = (b == 0) ? 0 : bpre[b - 1];
    int base = b * SCAN_CHUNK + t * 4;
    int v[4];
    int s = 0;
#pragma unroll
    for (int i = 0; i < 4; ++i) {
        int id = base + i;
        v[i] = (id < n) ? cnt[id] : 0;
        s += v[i];
    }
    tsum[t] = s;
    __syncthreads();
    for (int off = 1; off < 256; off <<= 1) {
        int u = (t >= off) ? tsum[t - off] : 0;
        __syncthreads();
        tsum[t] += u;
        __syncthreads();
    }
    int run = tsum[t] - s + block_base;
#pragma unroll
    for (int i = 0; i < 4; ++i) {
        int id = base + i;
        if (id < n) boff[id] = run;
        run += v[i];
    }
    if (b == 0 && t == 0) boff[n] = total;
}

// ---------------- scatter packed edges into per-part buckets ----------------
__global__ __launch_bounds__(256) void bucket_scatter(const int* __restrict__ ei, int E,
                                                      int chunk_size, int nxp,
                                                      const int* __restrict__ boff,
                                                      u32* __restrict__ bucket) {
    __shared__ int cur[MAXP];
    int t = threadIdx.x;
    for (int i = t; i < nxp; i += 256) cur[i] = boff[i * NCHUNK + blockIdx.x];
    __syncthreads();
    int base = blockIdx.x * chunk_size;
    int end = min(base + chunk_size, E);
    for (int e = base + t; e < end; e += 256) {
        int s = __builtin_nontemporal_load(&ei[e]);
        int d = __builtin_nontemporal_load(&ei[E + e]);
        int pos = atomicAdd(&cur[d >> PSHIFT], 1);
        bucket[pos] = ((u32)(d & (PSIZE - 1)) << SBITS) | (u32)s;
    }
}

// ---------------- counting-sort each partition slice -> nbr + row_ptr ----------------
__global__ __launch_bounds__(256) void sort_bucket(const u32* __restrict__ bucket,
                                                   const int* __restrict__ boff,
                                                   int* __restrict__ nbr,
                                                   int* __restrict__ row_ptr,
                                                   int n, int E) {
    __shared__ int cnt[PSIZE];
    __shared__ int sc[PSIZE];
    __shared__ int cur[PSIZE];
    int t = threadIdx.x;
    int p = blockIdx.x;
    if (t < PSIZE) cnt[t] = 0;
    __syncthreads();
    int beg = boff[p * NCHUNK];
    int end = boff[(p + 1) * NCHUNK];   // sentinel covers last partition
    for (int i = beg + t; i < end; i += 256)
        atomicAdd(&cnt[bucket[i] >> SBITS], 1);
    __syncthreads();
    if (t < PSIZE) sc[t] = cnt[t];
    __syncthreads();
    for (int off = 1; off < PSIZE; off <<= 1) {
        int v = 0;
        if (t < PSIZE && t >= off) v = sc[t - off];
        __syncthreads();
        if (t < PSIZE) sc[t] += v;
        __syncthreads();
    }
    if (t < PSIZE) {
        int excl = beg + sc[t] - cnt[t];
        cur[t] = excl;
        int node = p * PSIZE + t;
        if (node < n) row_ptr[node] = excl;
    }
    if (p == 0 && t == 0) row_ptr[n] = E;
    __syncthreads();
    for (int i = beg + t; i < end; i += 256) {
        u32 pk = bucket[i];
        int pos = atomicAdd(&cur[pk >> SBITS], 1);
        nbr[pos] = (int)(pk & SMASK);
    }
}

// ---------------- pull aggregation: shuffle-shared nbr, pipelined 8-edge batches ----------------
__global__ __launch_bounds__(256) void pull_bf16(const u16* __restrict__ Asrc,
                                                 const int* __restrict__ row_ptr,
                                                 const int* __restrict__ nbr,
                                                 u16* __restrict__ Adst, int n) {
    int tid = blockIdx.x * 256 + threadIdx.x;
    int node = tid >> 3;
    int q = tid & 7;
    if (node >= n) return;
    int beg = row_ptr[node], end = row_ptr[node + 1];
    float a0 = 0.f, a1 = 0.f, a2 = 0.f, a3 = 0.f, a4 = 0.f, a5 = 0.f, a6 = 0.f, a7 = 0.f;
    // software pipeline: load batch j0+8's indices while gathering batch j0
    int myj = beg + q;
    int snext = (myj < end) ? nbr[myj] : 0;
    for (int j0 = beg; j0 < end; j0 += 8) {
        int smine = snext;
        myj = j0 + 8 + q;
        snext = (myj < end) ? nbr[myj] : 0;
        int cnt = min(8, end - j0);
#pragma unroll 4
        for (int k = 0; k < cnt; ++k) {
            int s = __shfl(smine, k, 8);
            uint4 v = *(const uint4*)(Asrc + (size_t)s * 128 + 64 + q * 8);
            a0 += bf_lo(v.x); a1 += bf_hi(v.x);
            a2 += bf_lo(v.y); a3 += bf_hi(v.y);
            a4 += bf_lo(v.z); a5 += bf_hi(v.z);
            a6 += bf_lo(v.w); a7 += bf_hi(v.w);
        }
    }
    uint4 o;
    o.x = (u32)f2bf(a0) | ((u32)f2bf(a1) << 16);
    o.y = (u32)f2bf(a2) | ((u32)f2bf(a3) << 16);
    o.z = (u32)f2bf(a4) | ((u32)f2bf(a5) << 16);
    o.w = (u32)f2bf(a6) | ((u32)f2bf(a7) << 16);
    *(uint4*)(Adst + (size_t)node * 128 + q * 8) = o;
}

// ---------------- MFMA GEMM: [64 nodes] x [NT*16 cols], K=128 ----------------
// f32 output path: LDS-transpose epilogue -> coalesced row-major stores
template<int NT, bool RELU, bool OUT_BF16>
__global__ __launch_bounds__(256) void gemm_kernel(
    const u16* __restrict__ A, const u16* __restrict__ B,
    const float* __restrict__ bias,
    float* __restrict__ outf, u16* __restrict__ outb,
    int n_nodes, int n_cols)
{
    constexpr int KC = (NT == 16) ? 2 : 1;
    constexpr int KW = 128 / KC;
    constexpr int RG = KW / 8;
    constexpr int NR = NT * 16;
    __shared__ uint4 smem[3072];          // 48 KB: A_lds[0..1024) | B_lds[1024..3072)
    uint4* A_lds = smem;
    uint4* B_lds = smem + 1024;

    const int t = threadIdx.x;
    const int node0 = blockIdx.x * 64;

#pragma unroll
    for (int i = 0; i < 4; ++i) {
        int gl = t + 256 * i;
        int r = gl >> 4, g = gl & 15;
        uint4 v = make_uint4(0u, 0u, 0u, 0u);
        int node = node0 + r;
        if (node < n_nodes) v = *(const uint4*)(A + (size_t)node * 128 + g * 8);
        A_lds[r * 16 + (g ^ (r & 7))] = v;
    }

    const int w  = t >> 6;
    const int l  = t & 63;
    const int lm = l & 15;
    const int lg = l >> 4;
    const int arow = w * 16 + lm;
    const int asw  = arow & 7;

    f32x4 acc[NT];
#pragma unroll
    for (int n = 0; n < NT; ++n) acc[n] = f32x4{0.f, 0.f, 0.f, 0.f};

#pragma unroll
    for (int kc = 0; kc < KC; ++kc) {
        __syncthreads();
#pragma unroll
        for (int i = 0; i < (NR * RG) / 256; ++i) {
            int gl = t + 256 * i;
            int r = gl / RG, g = gl % RG;
            uint4 v = *(const uint4*)(B + (size_t)r * 128 + kc * KW + g * 8);
            B_lds[r * RG + (g ^ (r & 7))] = v;
        }
        __syncthreads();
#pragma unroll
        for (int ks = 0; ks < KW / 32; ++ks) {
            int ag = lg + (kc * (KW / 32) + ks) * 4;
            bf16x8 af = __builtin_bit_cast(bf16x8, A_lds[arow * 16 + (ag ^ asw)]);
#pragma unroll
            for (int n = 0; n < NT; ++n) {
                int brow = n * 16 + lm;
                int bg = lg + ks * 4;
                bf16x8 bf = __builtin_bit_cast(bf16x8, B_lds[brow * RG + (bg ^ (brow & 7))]);
                acc[n] = __builtin_amdgcn_mfma_f32_16x16x32_bf16(af, bf, acc[n], 0, 0, 0);
            }
        }
    }

    if (OUT_BF16) {
        const int rbase = w * 16 + lg * 4;
#pragma unroll
        for (int n = 0; n < NT; ++n) {
            int c = n * 16 + lm;
            float bv = (c < n_cols) ? bias[c] : 0.f;
#pragma unroll
            for (int r = 0; r < 4; ++r) {
                int node = node0 + rbase + r;
                if (node < n_nodes && c < n_cols) {
                    float v = acc[n][r] + bv;
                    if (RELU) v = fmaxf(v, 0.f);
                    outb[(size_t)node * 128 + 64 + c] = f2bf(v);
                }
            }
        }
    } else {
        float bc[NT];
#pragma unroll
        for (int n = 0; n < NT; ++n) {
            int c = n * 16 + lm;
            bc[n] = (c < n_cols) ? bias[c] : 0.f;
        }
        float* S = reinterpret_cast<float*>(smem);
        __syncthreads();
#pragma unroll
        for (int rc = 0; rc < 2; ++rc) {
            if (rc) __syncthreads();
            if ((lg >> 1) == rc) {
                int lrow = (lg & 1) * 4;
                float* Sw = S + ((size_t)w * 8 + lrow) * 264;
#pragma unroll
                for (int n = 0; n < NT; ++n) {
#pragma unroll
                    for (int r = 0; r < 4; ++r) {
                        float v = acc[n][r] + bc[n];
                        if (RELU) v = fmaxf(v, 0.f);
                        Sw[r * 264 + n * 16 + lm] = v;
                    }
                }
            }
            __syncthreads();
            const float* Sw = S + (size_t)w * 8 * 264;
#pragma unroll
            for (int row8 = 0; row8 < 8; ++row8) {
                int node = node0 + w * 16 + rc * 8 + row8;   // wave-uniform
                if (node >= n_nodes) continue;
                float* orow = outf + (size_t)node * (size_t)n_cols;
#pragma unroll
                for (int k = 0; k < 4; ++k) {
                    int c = k * 64 + l;
                    if (c < n_cols) orow[c] = Sw[row8 * 264 + c];
                }
            }
        }
    }
}

extern "C" void kernel_launch(void* const* d_in, const int* in_sizes, int n_in,
                              void* d_out, int out_size, void* d_ws, size_t ws_size,
                              hipStream_t stream) {
    const float* x   = (const float*)d_in[0];
    const int*   ei  = (const int*)d_in[1];
    const float* W1l = (const float*)d_in[2];
    const float* b1  = (const float*)d_in[3];
    const float* W1r = (const float*)d_in[4];
    const float* W2l = (const float*)d_in[5];
    const float* b2  = (const float*)d_in[6];
    const float* W2r = (const float*)d_in[7];
    float* out = (float*)d_out;

    const int N = in_sizes[0] / DIM;     // 100000  (< 2^17, required by packing)
    const int E = in_sizes[1] / 2;       // 1600000
    const int NPAD = ((N + 63) / 64) * 64;
    const int NXP = (N + PSIZE - 1) / PSIZE;          // 782 partitions
    const int NSC = NXP * NCHUNK;                     // 150144 scan entries
    const int NB2 = (NSC + SCAN_CHUNK - 1) / SCAN_CHUNK;   // 147 (<=256 required)

    // workspace layout
    char* wp = (char*)d_ws;
    u16* A1 = (u16*)wp;                 wp += (size_t)NPAD * 128 * 2;
    u16* A2 = (u16*)wp;                 wp += (size_t)NPAD * 128 * 2;
    u16* B1 = (u16*)wp;                 wp += 64 * 128 * 2;
    u16* B2 = (u16*)wp;                 wp += 256 * 128 * 2;
    int* bcnt = (int*)wp;               wp += (size_t)NSC * 4;
    int* boff = (int*)wp;               wp += (size_t)(NSC + 1) * 4;
    int* bsum = (int*)wp;               wp += 1024 * 4;
    int* row_ptr = (int*)wp;            wp += (size_t)(N + 1) * 4;
    u32* bucket = (u32*)wp;             wp += (size_t)E * 4;
    int* nbr = (int*)wp;                wp += (size_t)E * 4;

    const int chunk_size = (E + NCHUNK - 1) / NCHUNK;
    const int nx8 = N * 8;
    const int prep_items = nx8 + 64 * 128 + 256 * 128;
    const int prep_blocks = (prep_items + 255) / 256;

    // ---- fused histogram + prep ----
    build_kernel<<<NCHUNK + prep_blocks, 256, 0, stream>>>(
        ei + E, E, chunk_size, NXP, bcnt, x, A1, nx8, W1l, W1r, B1, W2l, W2r, B2);

    // ---- 2-launch scan ----
    scan_block_sums<<<NB2, 256, 0, stream>>>(bcnt, NSC, bsum);
    scan_final_boff<<<NB2, 256, 0, stream>>>(bcnt, NSC, bsum, NB2, boff, E);

    // ---- scatter + per-partition counting sort ----
    bucket_scatter<<<NCHUNK, 256, 0, stream>>>(ei, E, chunk_size, NXP, boff, bucket);
    sort_bucket<<<NXP, 256, 0, stream>>>(bucket, boff, nbr, row_ptr, N, E);

    const int gemm_blocks = NPAD / 64;

    // ---- layer 1 (pull at full occupancy, then GEMM) ----
    pull_bf16<<<(nx8 + 255) / 256, 256, 0, stream>>>(A1, row_ptr, nbr, A1, N);
    gemm_kernel<4, true, true><<<gemm_blocks, 256, 0, stream>>>(A1, B1, b1, nullptr, A2, N, 64);

    // ---- layer 2 (pull, then GEMM) ----
    pull_bf16<<<(nx8 + 255) / 256, 256, 0, stream>>>(A2, row_ptr, nbr, A2, N);
    gemm_kernel<16, false, false><<<gemm_blocks, 256, 0, stream>>>(A2, B2, b2, out, nullptr, N, NCLS);
}

// Round 13
// 191.996 us; speedup vs baseline: 1.3840x; 1.0279x over previous
//
#include <hip/hip_runtime.h>

#define DIM 64
#define NCLS 249
#define SCAN_CHUNK 1024
#define NCHUNK 192
#define PSHIFT 7
#define PSIZE 128
#define SBITS 17
#define SMASK ((1u << SBITS) - 1)
#define MAXP 1024   // max partitions (N <= 131072)

typedef unsigned int u32;
typedef unsigned short u16;
using bf16x8 = __attribute__((ext_vector_type(8))) short;
using f32x4  = __attribute__((ext_vector_type(4))) float;

__device__ __forceinline__ u16 f2bf(float f) {
    u32 u = __builtin_bit_cast(u32, f);
    u += 0x7FFFu + ((u >> 16) & 1u);   // round-to-nearest-even
    return (u16)(u >> 16);
}
__device__ __forceinline__ float bf_lo(u32 u) { return __builtin_bit_cast(float, u << 16); }
__device__ __forceinline__ float bf_hi(u32 u) { return __builtin_bit_cast(float, u & 0xFFFF0000u); }

// ---------------- fused: per-(chunk,part) edge counts + prep (x->bf16, B1, B2) ----------------
__global__ __launch_bounds__(256) void build_kernel(
    const int* __restrict__ dst, int E, int chunk_size, int nxp,
    int* __restrict__ bcnt,
    const float* __restrict__ x, u16* __restrict__ A1, int nx8,
    const float* __restrict__ W1l, const float* __restrict__ W1r, u16* __restrict__ B1,
    const float* __restrict__ W2l, const float* __restrict__ W2r, u16* __restrict__ B2)
{
    __shared__ int c[MAXP];
    int t = threadIdx.x;
    if (blockIdx.x < NCHUNK) {
        for (int i = t; i < nxp; i += 256) c[i] = 0;
        __syncthreads();
        int base = blockIdx.x * chunk_size;
        int end = min(base + chunk_size, E);
        for (int e = base + t; e < end; e += 256) {
            int d = __builtin_nontemporal_load(&dst[e]);
            atomicAdd(&c[d >> PSHIFT], 1);
        }
        __syncthreads();
        for (int i = t; i < nxp; i += 256) bcnt[i * NCHUNK + blockIdx.x] = c[i];
        return;
    }
    int i = (blockIdx.x - NCHUNK) * 256 + t;
    if (i < nx8) {
        int node = i >> 3, seg = i & 7;
        const float4 v0 = *(const float4*)(x + (size_t)i * 8);
        const float4 v1 = *(const float4*)(x + (size_t)i * 8 + 4);
        uint4 o;
        o.x = (u32)f2bf(v0.x) | ((u32)f2bf(v0.y) << 16);
        o.y = (u32)f2bf(v0.z) | ((u32)f2bf(v0.w) << 16);
        o.z = (u32)f2bf(v1.x) | ((u32)f2bf(v1.y) << 16);
        o.w = (u32)f2bf(v1.z) | ((u32)f2bf(v1.w) << 16);
        *(uint4*)(A1 + (size_t)node * 128 + 64 + seg * 8) = o;
        return;
    }
    int j = i - nx8;
    if (j < 64 * 128) {
        int r = j >> 7, k = j & 127;
        B1[j] = f2bf(k < 64 ? W1l[r * 64 + k] : W1r[r * 64 + k - 64]);
        return;
    }
    j -= 64 * 128;
    if (j < 256 * 128) {
        int r = j >> 7, k = j & 127;
        float v = 0.f;
        if (r < NCLS) v = (k < 64) ? W2l[r * 64 + k] : W2r[r * 64 + k - 64];
        B2[j] = f2bf(v);
    }
}

// ---------------- scan level 1: per-1024-chunk sums ----------------
__global__ __launch_bounds__(256) void scan_block_sums(const int* __restrict__ cnt, int n,
                                                       int* __restrict__ bsum) {
    __shared__ int sdata[256];
    int b = blockIdx.x, t = threadIdx.x;
    int base = b * SCAN_CHUNK;
    int s = 0;
    for (int i = t; i < SCAN_CHUNK; i += 256) {
        int idx = base + i;
        s += (idx < n) ? cnt[idx] : 0;
    }
    sdata[t] = s;
    __syncthreads();
    for (int off = 128; off > 0; off >>= 1) {
        if (t < off) sdata[t] += sdata[t + off];
        __syncthreads();
    }
    if (t == 0) bsum[b] = sdata[0];
}

// ---------------- scan level 2: final, self-scanning raw bsum (nb <= 256) ----------------
__global__ __launch_bounds__(256) void scan_final_boff(const int* __restrict__ cnt, int n,
                                                       const int* __restrict__ bsum_raw, int nb,
                                                       int* __restrict__ boff, int total) {
    __shared__ int bpre[256];
    __shared__ int tsum[256];
    int b = blockIdx.x, t = threadIdx.x;
    int bv = (t < nb) ? bsum_raw[t] : 0;
    bpre[t] = bv;
    __syncthreads();
    for (int off = 1; off < 256; off <<= 1) {
        int u = (t >= off) ? bpre[t - off] : 0;
        __syncthreads();
        bpre[t] += u;
        __syncthreads();
    }
    int block_base = (b == 0) ? 0 : bpre[b - 1];
    int base = b * SCAN_CHUNK + t * 4;
    int v[4];
    int s = 0;
#pragma unroll
    for (int i = 0; i < 4; ++i) {
        int id = base + i;
        v[i] = (id < n) ? cnt[id] : 0;
        s += v[i];
    }
    tsum[t] = s;
    __syncthreads();
    for (int off = 1; off < 256; off <<= 1) {
        int u = (t >= off) ? tsum[t - off] : 0;
        __syncthreads();
        tsum[t] += u;
        __syncthreads();
    }
    int run = tsum[t] - s + block_base;
#pragma unroll
    for (int i = 0; i < 4; ++i) {
        int id = base + i;
        if (id < n) boff[id] = run;
        run += v[i];
    }
    if (b == 0 && t == 0) boff[n] = total;
}

// ---------------- scatter packed edges into per-part buckets ----------------
__global__ __launch_bounds__(256) void bucket_scatter(const int* __restrict__ ei, int E,
                                                      int chunk_size, int nxp,
                                                      const int* __restrict__ boff,
                                                      u32* __restrict__ bucket) {
    __shared__ int cur[MAXP];
    int t = threadIdx.x;
    for (int i = t; i < nxp; i += 256) cur[i] = boff[i * NCHUNK + blockIdx.x];
    __syncthreads();
    int base = blockIdx.x * chunk_size;
    int end = min(base + chunk_size, E);
    for (int e = base + t; e < end; e += 256) {
        int s = __builtin_nontemporal_load(&ei[e]);
        int d = __builtin_nontemporal_load(&ei[E + e]);
        int pos = atomicAdd(&cur[d >> PSHIFT], 1);
        bucket[pos] = ((u32)(d & (PSIZE - 1)) << SBITS) | (u32)s;
    }
}

// ---------------- counting-sort each partition slice -> nbr + row_ptr ----------------
__global__ __launch_bounds__(256) void sort_bucket(const u32* __restrict__ bucket,
                                                   const int* __restrict__ boff,
                                                   int* __restrict__ nbr,
                                                   int* __restrict__ row_ptr,
                                                   int n, int E) {
    __shared__ int cnt[PSIZE];
    __shared__ int sc[PSIZE];
    __shared__ int cur[PSIZE];
    int t = threadIdx.x;
    int p = blockIdx.x;
    if (t < PSIZE) cnt[t] = 0;
    __syncthreads();
    int beg = boff[p * NCHUNK];
    int end = boff[(p + 1) * NCHUNK];   // sentinel covers last partition
    for (int i = beg + t; i < end; i += 256)
        atomicAdd(&cnt[bucket[i] >> SBITS], 1);
    __syncthreads();
    if (t < PSIZE) sc[t] = cnt[t];
    __syncthreads();
    for (int off = 1; off < PSIZE; off <<= 1) {
        int v = 0;
        if (t < PSIZE && t >= off) v = sc[t - off];
        __syncthreads();
        if (t < PSIZE) sc[t] += v;
        __syncthreads();
    }
    if (t < PSIZE) {
        int excl = beg + sc[t] - cnt[t];
        cur[t] = excl;
        int node = p * PSIZE + t;
        if (node < n) row_ptr[node] = excl;
    }
    if (p == 0 && t == 0) row_ptr[n] = E;
    __syncthreads();
    for (int i = beg + t; i < end; i += 256) {
        u32 pk = bucket[i];
        int pos = atomicAdd(&cur[pk >> SBITS], 1);
        nbr[pos] = (int)(pk & SMASK);
    }
}

// ---------------- pull aggregation: shuffle-shared nbr, pipelined 8-edge batches ----------------
__global__ __launch_bounds__(256) void pull_bf16(const u16* __restrict__ Asrc,
                                                 const int* __restrict__ row_ptr,
                                                 const int* __restrict__ nbr,
                                                 u16* __restrict__ Adst, int n) {
    int tid = blockIdx.x * 256 + threadIdx.x;
    int node = tid >> 3;
    int q = tid & 7;
    if (node >= n) return;
    int beg = row_ptr[node], end = row_ptr[node + 1];
    float a0 = 0.f, a1 = 0.f, a2 = 0.f, a3 = 0.f, a4 = 0.f, a5 = 0.f, a6 = 0.f, a7 = 0.f;
    // software pipeline: load batch j0+8's indices while gathering batch j0
    int myj = beg + q;
    int snext = (myj < end) ? nbr[myj] : 0;
    for (int j0 = beg; j0 < end; j0 += 8) {
        int smine = snext;
        myj = j0 + 8 + q;
        snext = (myj < end) ? nbr[myj] : 0;
        if (j0 + 8 <= end) {
            // full batch: compile-time unroll, 8 independent gathers in flight
#pragma unroll
            for (int k = 0; k < 8; ++k) {
                int s = __shfl(smine, k, 8);
                uint4 v = *(const uint4*)(Asrc + (size_t)s * 128 + 64 + q * 8);
                a0 += bf_lo(v.x); a1 += bf_hi(v.x);
                a2 += bf_lo(v.y); a3 += bf_hi(v.y);
                a4 += bf_lo(v.z); a5 += bf_hi(v.z);
                a6 += bf_lo(v.w); a7 += bf_hi(v.w);
            }
        } else {
            int cnt = end - j0;
            for (int k = 0; k < cnt; ++k) {
                int s = __shfl(smine, k, 8);
                uint4 v = *(const uint4*)(Asrc + (size_t)s * 128 + 64 + q * 8);
                a0 += bf_lo(v.x); a1 += bf_hi(v.x);
                a2 += bf_lo(v.y); a3 += bf_hi(v.y);
                a4 += bf_lo(v.z); a5 += bf_hi(v.z);
                a6 += bf_lo(v.w); a7 += bf_hi(v.w);
            }
        }
    }
    uint4 o;
    o.x = (u32)f2bf(a0) | ((u32)f2bf(a1) << 16);
    o.y = (u32)f2bf(a2) | ((u32)f2bf(a3) << 16);
    o.z = (u32)f2bf(a4) | ((u32)f2bf(a5) << 16);
    o.w = (u32)f2bf(a6) | ((u32)f2bf(a7) << 16);
    *(uint4*)(Adst + (size_t)node * 128 + q * 8) = o;
}

// ---------------- layer-1 MFMA GEMM: [64 nodes] x [64 cols], K=128, bf16 out ----------------
__global__ __launch_bounds__(256) void gemm1_kernel(
    const u16* __restrict__ A, const u16* __restrict__ B,
    const float* __restrict__ bias, u16* __restrict__ outb, int n_nodes)
{
    constexpr int NT = 4;
    __shared__ uint4 A_lds[1024];         // 64 rows x 16 granules
    __shared__ uint4 B_lds[1024];         // 64 rows x 16 granules

    const int t = threadIdx.x;
    const int node0 = blockIdx.x * 64;

#pragma unroll
    for (int i = 0; i < 4; ++i) {
        int gl = t + 256 * i;
        int r = gl >> 4, g = gl & 15;
        uint4 v = make_uint4(0u, 0u, 0u, 0u);
        int node = node0 + r;
        if (node < n_nodes) v = *(const uint4*)(A + (size_t)node * 128 + g * 8);
        A_lds[r * 16 + (g ^ (r & 7))] = v;
    }
#pragma unroll
    for (int i = 0; i < 4; ++i) {
        int gl = t + 256 * i;
        int r = gl >> 4, g = gl & 15;
        B_lds[r * 16 + (g ^ (r & 7))] = *(const uint4*)(B + (size_t)r * 128 + g * 8);
    }

    const int w  = t >> 6;
    const int l  = t & 63;
    const int lm = l & 15;
    const int lg = l >> 4;
    const int arow = w * 16 + lm;
    const int asw  = arow & 7;

    f32x4 acc[NT];
#pragma unroll
    for (int n = 0; n < NT; ++n) acc[n] = f32x4{0.f, 0.f, 0.f, 0.f};

    __syncthreads();
#pragma unroll
    for (int ks = 0; ks < 4; ++ks) {
        int ag = lg + ks * 4;
        bf16x8 af = __builtin_bit_cast(bf16x8, A_lds[arow * 16 + (ag ^ asw)]);
#pragma unroll
        for (int n = 0; n < NT; ++n) {
            int brow = n * 16 + lm;
            bf16x8 bf = __builtin_bit_cast(bf16x8, B_lds[brow * 16 + (ag ^ (brow & 7))]);
            acc[n] = __builtin_amdgcn_mfma_f32_16x16x32_bf16(af, bf, acc[n], 0, 0, 0);
        }
    }

    // D col = lane&15 (+tile*16), row = (lane>>4)*4+reg (+wave*16)
    const int rbase = w * 16 + lg * 4;
#pragma unroll
    for (int n = 0; n < NT; ++n) {
        int c = n * 16 + lm;
        float bv = bias[c];
#pragma unroll
        for (int r = 0; r < 4; ++r) {
            int node = node0 + rbase + r;
            if (node < n_nodes) {
                float v = fmaxf(acc[n][r] + bv, 0.f);
                outb[(size_t)node * 128 + 64 + c] = f2bf(v);
            }
        }
    }
}

// ---------------- layer-2 MFMA GEMM, split-N: [64 nodes] x [128 cols/block] ----------------
// grid.y in {0,1} selects the column half; KC=1 (single B staging);
// f32 LDS-transpose epilogue -> coalesced row stores.
__global__ __launch_bounds__(256) void gemm2_kernel(
    const u16* __restrict__ A, const u16* __restrict__ B,
    const float* __restrict__ bias, float* __restrict__ outf, int n_nodes)
{
    constexpr int NT = 8;
    __shared__ uint4 smem[3072];          // 48 KB: A_lds[0..1024) | B_lds[1024..3072)
    uint4* A_lds = smem;
    uint4* B_lds = smem + 1024;

    const int t = threadIdx.x;
    const int node0 = blockIdx.x * 64;
    const int cbase = blockIdx.y * 128;   // column-half offset

#pragma unroll
    for (int i = 0; i < 4; ++i) {
        int gl = t + 256 * i;
        int r = gl >> 4, g = gl & 15;
        uint4 v = make_uint4(0u, 0u, 0u, 0u);
        int node = node0 + r;
        if (node < n_nodes) v = *(const uint4*)(A + (size_t)node * 128 + g * 8);
        A_lds[r * 16 + (g ^ (r & 7))] = v;
    }
    // B rows cbase..cbase+127, full K=128
#pragma unroll
    for (int i = 0; i < 8; ++i) {
        int gl = t + 256 * i;
        int r = gl >> 4, g = gl & 15;
        B_lds[r * 16 + (g ^ (r & 7))] = *(const uint4*)(B + (size_t)(cbase + r) * 128 + g * 8);
    }

    const int w  = t >> 6;
    const int l  = t & 63;
    const int lm = l & 15;
    const int lg = l >> 4;
    const int arow = w * 16 + lm;
    const int asw  = arow & 7;

    f32x4 acc[NT];
#pragma unroll
    for (int n = 0; n < NT; ++n) acc[n] = f32x4{0.f, 0.f, 0.f, 0.f};

    __syncthreads();
#pragma unroll
    for (int ks = 0; ks < 4; ++ks) {
        int ag = lg + ks * 4;
        bf16x8 af = __builtin_bit_cast(bf16x8, A_lds[arow * 16 + (ag ^ asw)]);
#pragma unroll
        for (int n = 0; n < NT; ++n) {
            int brow = n * 16 + lm;
            bf16x8 bf = __builtin_bit_cast(bf16x8, B_lds[brow * 16 + (ag ^ (brow & 7))]);
            acc[n] = __builtin_amdgcn_mfma_f32_16x16x32_bf16(af, bf, acc[n], 0, 0, 0);
        }
    }

    // epilogue: stage per-wave 16x128 into LDS (2 chunks of 8 rows), stride 132
    float bc[NT];
#pragma unroll
    for (int n = 0; n < NT; ++n) {
        int c = cbase + n * 16 + lm;
        bc[n] = (c < NCLS) ? bias[c] : 0.f;
    }
    float* S = reinterpret_cast<float*>(smem);   // 4 waves x 8 rows x 132 = 16.9 KB
    __syncthreads();   // all waves done reading A_lds/B_lds
#pragma unroll
    for (int rc = 0; rc < 2; ++rc) {
        if (rc) __syncthreads();               // WAR: previous chunk's reads done
        if ((lg >> 1) == rc) {                 // lg {0,1} -> rows 0..7; {2,3} -> 8..15
            int lrow = (lg & 1) * 4;
            float* Sw = S + ((size_t)w * 8 + lrow) * 132;
#pragma unroll
            for (int n = 0; n < NT; ++n) {
#pragma unroll
                for (int r = 0; r < 4; ++r) {
                    Sw[r * 132 + n * 16 + lm] = acc[n][r] + bc[n];
                }
            }
        }
        __syncthreads();                       // staged rows visible
        const float* Sw = S + (size_t)w * 8 * 132;
#pragma unroll
        for (int row8 = 0; row8 < 8; ++row8) {
            int node = node0 + w * 16 + rc * 8 + row8;   // wave-uniform
            if (node >= n_nodes) continue;
            float* orow = outf + (size_t)node * NCLS + cbase;
#pragma unroll
            for (int k = 0; k < 2; ++k) {
                int c = k * 64 + l;            // lanes cover 64 consecutive cols
                if (cbase + c < NCLS) orow[c] = Sw[row8 * 132 + c];
            }
        }
    }
}

extern "C" void kernel_launch(void* const* d_in, const int* in_sizes, int n_in,
                              void* d_out, int out_size, void* d_ws, size_t ws_size,
                              hipStream_t stream) {
    const float* x   = (const float*)d_in[0];
    const int*   ei  = (const int*)d_in[1];
    const float* W1l = (const float*)d_in[2];
    const float* b1  = (const float*)d_in[3];
    const float* W1r = (const float*)d_in[4];
    const float* W2l = (const float*)d_in[5];
    const float* b2  = (const float*)d_in[6];
    const float* W2r = (const float*)d_in[7];
    float* out = (float*)d_out;

    const int N = in_sizes[0] / DIM;     // 100000  (< 2^17, required by packing)
    const int E = in_sizes[1] / 2;       // 1600000
    const int NPAD = ((N + 63) / 64) * 64;
    const int NXP = (N + PSIZE - 1) / PSIZE;          // 782 partitions
    const int NSC = NXP * NCHUNK;                     // 150144 scan entries
    const int NB2 = (NSC + SCAN_CHUNK - 1) / SCAN_CHUNK;   // 147 (<=256 required)

    // workspace layout
    char* wp = (char*)d_ws;
    u16* A1 = (u16*)wp;                 wp += (size_t)NPAD * 128 * 2;
    u16* A2 = (u16*)wp;                 wp += (size_t)NPAD * 128 * 2;
    u16* B1 = (u16*)wp;                 wp += 64 * 128 * 2;
    u16* B2 = (u16*)wp;                 wp += 256 * 128 * 2;
    int* bcnt = (int*)wp;               wp += (size_t)NSC * 4;
    int* boff = (int*)wp;               wp += (size_t)(NSC + 1) * 4;
    int* bsum = (int*)wp;               wp += 1024 * 4;
    int* row_ptr = (int*)wp;            wp += (size_t)(N + 1) * 4;
    u32* bucket = (u32*)wp;             wp += (size_t)E * 4;
    int* nbr = (int*)wp;                wp += (size_t)E * 4;

    const int chunk_size = (E + NCHUNK - 1) / NCHUNK;
    const int nx8 = N * 8;
    const int prep_items = nx8 + 64 * 128 + 256 * 128;
    const int prep_blocks = (prep_items + 255) / 256;

    // ---- fused histogram + prep ----
    build_kernel<<<NCHUNK + prep_blocks, 256, 0, stream>>>(
        ei + E, E, chunk_size, NXP, bcnt, x, A1, nx8, W1l, W1r, B1, W2l, W2r, B2);

    // ---- 2-launch scan ----
    scan_block_sums<<<NB2, 256, 0, stream>>>(bcnt, NSC, bsum);
    scan_final_boff<<<NB2, 256, 0, stream>>>(bcnt, NSC, bsum, NB2, boff, E);

    // ---- scatter + per-partition counting sort ----
    bucket_scatter<<<NCHUNK, 256, 0, stream>>>(ei, E, chunk_size, NXP, boff, bucket);
    sort_bucket<<<NXP, 256, 0, stream>>>(bucket, boff, nbr, row_ptr, N, E);

    const int gemm_blocks = NPAD / 64;

    // ---- layer 1 (pull at full occupancy, then GEMM) ----
    pull_bf16<<<(nx8 + 255) / 256, 256, 0, stream>>>(A1, row_ptr, nbr, A1, N);
    gemm1_kernel<<<gemm_blocks, 256, 0, stream>>>(A1, B1, b1, A2, N);

    // ---- layer 2 (pull, then split-N GEMM) ----
    pull_bf16<<<(nx8 + 255) / 256, 256, 0, stream>>>(A2, row_ptr, nbr, A2, N);
    gemm2_kernel<<<dim3(gemm_blocks, 2), 256, 0, stream>>>(A2, B2, b2, out, N);
}

// Round 14
// 185.791 us; speedup vs baseline: 1.4302x; 1.0334x over previous
//
#include <hip/hip_runtime.h>

#define DIM 64
#define NCLS 249
#define SCAN_CHUNK 1024
#define NCHUNK 192
#define PSHIFT 8
#define PSIZE 256
#define SBITS 17
#define SMASK ((1u << SBITS) - 1)
#define MAXP 512    // max partitions (N <= 131072)

typedef unsigned int u32;
typedef unsigned short u16;
using bf16x8 = __attribute__((ext_vector_type(8))) short;
using f32x4  = __attribute__((ext_vector_type(4))) float;

__device__ __forceinline__ u16 f2bf(float f) {
    u32 u = __builtin_bit_cast(u32, f);
    u += 0x7FFFu + ((u >> 16) & 1u);   // round-to-nearest-even
    return (u16)(u >> 16);
}
__device__ __forceinline__ float bf_lo(u32 u) { return __builtin_bit_cast(float, u << 16); }
__device__ __forceinline__ float bf_hi(u32 u) { return __builtin_bit_cast(float, u & 0xFFFF0000u); }

// ---------------- fused: per-(chunk,part) edge counts + prep (x->bf16, B1, B2) ----------------
__global__ __launch_bounds__(256) void build_kernel(
    const int* __restrict__ dst, int E, int chunk_size, int nxp,
    int* __restrict__ bcnt,
    const float* __restrict__ x, u16* __restrict__ A1, int nx8,
    const float* __restrict__ W1l, const float* __restrict__ W1r, u16* __restrict__ B1,
    const float* __restrict__ W2l, const float* __restrict__ W2r, u16* __restrict__ B2)
{
    __shared__ int c[MAXP];
    int t = threadIdx.x;
    if (blockIdx.x < NCHUNK) {
        for (int i = t; i < nxp; i += 256) c[i] = 0;
        __syncthreads();
        int base = blockIdx.x * chunk_size;
        int end = min(base + chunk_size, E);
        for (int e = base + t; e < end; e += 256) {
            int d = __builtin_nontemporal_load(&dst[e]);
            atomicAdd(&c[d >> PSHIFT], 1);
        }
        __syncthreads();
        for (int i = t; i < nxp; i += 256) bcnt[i * NCHUNK + blockIdx.x] = c[i];
        return;
    }
    int i = (blockIdx.x - NCHUNK) * 256 + t;
    if (i < nx8) {
        int node = i >> 3, seg = i & 7;
        const float4 v0 = *(const float4*)(x + (size_t)i * 8);
        const float4 v1 = *(const float4*)(x + (size_t)i * 8 + 4);
        uint4 o;
        o.x = (u32)f2bf(v0.x) | ((u32)f2bf(v0.y) << 16);
        o.y = (u32)f2bf(v0.z) | ((u32)f2bf(v0.w) << 16);
        o.z = (u32)f2bf(v1.x) | ((u32)f2bf(v1.y) << 16);
        o.w = (u32)f2bf(v1.z) | ((u32)f2bf(v1.w) << 16);
        *(uint4*)(A1 + (size_t)node * 128 + 64 + seg * 8) = o;
        return;
    }
    int j = i - nx8;
    if (j < 64 * 128) {
        int r = j >> 7, k = j & 127;
        B1[j] = f2bf(k < 64 ? W1l[r * 64 + k] : W1r[r * 64 + k - 64]);
        return;
    }
    j -= 64 * 128;
    if (j < 256 * 128) {
        int r = j >> 7, k = j & 127;
        float v = 0.f;
        if (r < NCLS) v = (k < 64) ? W2l[r * 64 + k] : W2r[r * 64 + k - 64];
        B2[j] = f2bf(v);
    }
}

// ---------------- scan level 1: per-1024-chunk sums ----------------
__global__ __launch_bounds__(256) void scan_block_sums(const int* __restrict__ cnt, int n,
                                                       int* __restrict__ bsum) {
    __shared__ int sdata[256];
    int b = blockIdx.x, t = threadIdx.x;
    int base = b * SCAN_CHUNK;
    int s = 0;
    for (int i = t; i < SCAN_CHUNK; i += 256) {
        int idx = base + i;
        s += (idx < n) ? cnt[idx] : 0;
    }
    sdata[t] = s;
    __syncthreads();
    for (int off = 128; off > 0; off >>= 1) {
        if (t < off) sdata[t] += sdata[t + off];
        __syncthreads();
    }
    if (t == 0) bsum[b] = sdata[0];
}

// ---------------- scan level 2: final, self-scanning raw bsum (nb <= 256) ----------------
__global__ __launch_bounds__(256) void scan_final_boff(const int* __restrict__ cnt, int n,
                                                       const int* __restrict__ bsum_raw, int nb,
                                                       int* __restrict__ boff, int total) {
    __shared__ int bpre[256];
    __shared__ int tsum[256];
    int b = blockIdx.x, t = threadIdx.x;
    int bv = (t < nb) ? bsum_raw[t] : 0;
    bpre[t] = bv;
    __syncthreads();
    for (int off = 1; off < 256; off <<= 1) {
        int u = (t >= off) ? bpre[t - off] : 0;
        __syncthreads();
        bpre[t] += u;
        __syncthreads();
    }
    int block_base = (b == 0) ? 0 : bpre[b - 1];
    int base = b * SCAN_CHUNK + t * 4;
    int v[4];
    int s = 0;
#pragma unroll
    for (int i = 0; i < 4; ++i) {
        int id = base + i;
        v[i] = (id < n) ? cnt[id] : 0;
        s += v[i];
    }
    tsum[t] = s;
    __syncthreads();
    for (int off = 1; off < 256; off <<= 1) {
        int u = (t >= off) ? tsum[t - off] : 0;
        __syncthreads();
        tsum[t] += u;
        __syncthreads();
    }
    int run = tsum[t] - s + block_base;
#pragma unroll
    for (int i = 0; i < 4; ++i) {
        int id = base + i;
        if (id < n) boff[id] = run;
        run += v[i];
    }
    if (b == 0 && t == 0) boff[n] = total;
}

// ---------------- scatter packed edges into per-part buckets ----------------
__global__ __launch_bounds__(256) void bucket_scatter(const int* __restrict__ ei, int E,
                                                      int chunk_size, int nxp,
                                                      const int* __restrict__ boff,
                                                      u32* __restrict__ bucket) {
    __shared__ int cur[MAXP];
    int t = threadIdx.x;
    for (int i = t; i < nxp; i += 256) cur[i] = boff[i * NCHUNK + blockIdx.x];
    __syncthreads();
    int base = blockIdx.x * chunk_size;
    int end = min(base + chunk_size, E);
    for (int e = base + t; e < end; e += 256) {
        int s = __builtin_nontemporal_load(&ei[e]);
        int d = __builtin_nontemporal_load(&ei[E + e]);
        int pos = atomicAdd(&cur[d >> PSHIFT], 1);
        bucket[pos] = ((u32)(d & (PSIZE - 1)) << SBITS) | (u32)s;
    }
}

// ---------------- counting-sort each partition slice -> nbr + row_ptr ----------------
__global__ __launch_bounds__(256) void sort_bucket(const u32* __restrict__ bucket,
                                                   const int* __restrict__ boff,
                                                   int* __restrict__ nbr,
                                                   int* __restrict__ row_ptr,
                                                   int n, int E) {
    __shared__ int cnt[PSIZE];
    __shared__ int sc[PSIZE];
    __shared__ int cur[PSIZE];
    int t = threadIdx.x;
    int p = blockIdx.x;
    cnt[t] = 0;
    __syncthreads();
    int beg = boff[p * NCHUNK];
    int end = boff[(p + 1) * NCHUNK];   // sentinel covers last partition
    for (int i = beg + t; i < end; i += 256)
        atomicAdd(&cnt[bucket[i] >> SBITS], 1);
    __syncthreads();
    sc[t] = cnt[t];
    __syncthreads();
    for (int off = 1; off < PSIZE; off <<= 1) {
        int v = (t >= off) ? sc[t - off] : 0;
        __syncthreads();
        sc[t] += v;
        __syncthreads();
    }
    {
        int excl = beg + sc[t] - cnt[t];
        cur[t] = excl;
        int node = p * PSIZE + t;
        if (node < n) row_ptr[node] = excl;
    }
    if (p == 0 && t == 0) row_ptr[n] = E;
    __syncthreads();
    for (int i = beg + t; i < end; i += 256) {
        u32 pk = bucket[i];
        int pos = atomicAdd(&cur[pk >> SBITS], 1);
        nbr[pos] = (int)(pk & SMASK);
    }
}

// ---------------- pull aggregation: shuffle-shared nbr, pipelined 8-edge batches ----------------
__global__ __launch_bounds__(256) void pull_bf16(const u16* __restrict__ Asrc,
                                                 const int* __restrict__ row_ptr,
                                                 const int* __restrict__ nbr,
                                                 u16* __restrict__ Adst, int n) {
    int tid = blockIdx.x * 256 + threadIdx.x;
    int node = tid >> 3;
    int q = tid & 7;
    if (node >= n) return;
    int beg = row_ptr[node], end = row_ptr[node + 1];
    float a0 = 0.f, a1 = 0.f, a2 = 0.f, a3 = 0.f, a4 = 0.f, a5 = 0.f, a6 = 0.f, a7 = 0.f;
    // software pipeline: load batch j0+8's indices while gathering batch j0
    int myj = beg + q;
    int snext = (myj < end) ? nbr[myj] : 0;
    for (int j0 = beg; j0 < end; j0 += 8) {
        int smine = snext;
        myj = j0 + 8 + q;
        snext = (myj < end) ? nbr[myj] : 0;
        if (j0 + 8 <= end) {
#pragma unroll
            for (int k = 0; k < 8; ++k) {
                int s = __shfl(smine, k, 8);
                uint4 v = *(const uint4*)(Asrc + (size_t)s * 128 + 64 + q * 8);
                a0 += bf_lo(v.x); a1 += bf_hi(v.x);
                a2 += bf_lo(v.y); a3 += bf_hi(v.y);
                a4 += bf_lo(v.z); a5 += bf_hi(v.z);
                a6 += bf_lo(v.w); a7 += bf_hi(v.w);
            }
        } else {
            int cnt = end - j0;
            for (int k = 0; k < cnt; ++k) {
                int s = __shfl(smine, k, 8);
                uint4 v = *(const uint4*)(Asrc + (size_t)s * 128 + 64 + q * 8);
                a0 += bf_lo(v.x); a1 += bf_hi(v.x);
                a2 += bf_lo(v.y); a3 += bf_hi(v.y);
                a4 += bf_lo(v.z); a5 += bf_hi(v.z);
                a6 += bf_lo(v.w); a7 += bf_hi(v.w);
            }
        }
    }
    uint4 o;
    o.x = (u32)f2bf(a0) | ((u32)f2bf(a1) << 16);
    o.y = (u32)f2bf(a2) | ((u32)f2bf(a3) << 16);
    o.z = (u32)f2bf(a4) | ((u32)f2bf(a5) << 16);
    o.w = (u32)f2bf(a6) | ((u32)f2bf(a7) << 16);
    *(uint4*)(Adst + (size_t)node * 128 + q * 8) = o;
}

// ---------------- layer-1 MFMA GEMM: [64 nodes] x [64 cols], K=128, bf16 out ----------------
__global__ __launch_bounds__(256) void gemm1_kernel(
    const u16* __restrict__ A, const u16* __restrict__ B,
    const float* __restrict__ bias, u16* __restrict__ outb, int n_nodes)
{
    constexpr int NT = 4;
    __shared__ uint4 A_lds[1024];         // 64 rows x 16 granules
    __shared__ uint4 B_lds[1024];         // 64 rows x 16 granules

    const int t = threadIdx.x;
    const int node0 = blockIdx.x * 64;

#pragma unroll
    for (int i = 0; i < 4; ++i) {
        int gl = t + 256 * i;
        int r = gl >> 4, g = gl & 15;
        uint4 v = make_uint4(0u, 0u, 0u, 0u);
        int node = node0 + r;
        if (node < n_nodes) v = *(const uint4*)(A + (size_t)node * 128 + g * 8);
        A_lds[r * 16 + (g ^ (r & 7))] = v;
    }
#pragma unroll
    for (int i = 0; i < 4; ++i) {
        int gl = t + 256 * i;
        int r = gl >> 4, g = gl & 15;
        B_lds[r * 16 + (g ^ (r & 7))] = *(const uint4*)(B + (size_t)r * 128 + g * 8);
    }

    const int w  = t >> 6;
    const int l  = t & 63;
    const int lm = l & 15;
    const int lg = l >> 4;
    const int arow = w * 16 + lm;
    const int asw  = arow & 7;

    f32x4 acc[NT];
#pragma unroll
    for (int n = 0; n < NT; ++n) acc[n] = f32x4{0.f, 0.f, 0.f, 0.f};

    __syncthreads();
#pragma unroll
    for (int ks = 0; ks < 4; ++ks) {
        int ag = lg + ks * 4;
        bf16x8 af = __builtin_bit_cast(bf16x8, A_lds[arow * 16 + (ag ^ asw)]);
#pragma unroll
        for (int n = 0; n < NT; ++n) {
            int brow = n * 16 + lm;
            bf16x8 bf = __builtin_bit_cast(bf16x8, B_lds[brow * 16 + (ag ^ (brow & 7))]);
            acc[n] = __builtin_amdgcn_mfma_f32_16x16x32_bf16(af, bf, acc[n], 0, 0, 0);
        }
    }

    // D col = lane&15 (+tile*16), row = (lane>>4)*4+reg (+wave*16)
    const int rbase = w * 16 + lg * 4;
#pragma unroll
    for (int n = 0; n < NT; ++n) {
        int c = n * 16 + lm;
        float bv = bias[c];
#pragma unroll
        for (int r = 0; r < 4; ++r) {
            int node = node0 + rbase + r;
            if (node < n_nodes) {
                float v = fmaxf(acc[n][r] + bv, 0.f);
                outb[(size_t)node * 128 + 64 + c] = f2bf(v);
            }
        }
    }
}

// ---------------- layer-2 MFMA GEMM, split-N: [64 nodes] x [128 cols/block] ----------------
__global__ __launch_bounds__(256) void gemm2_kernel(
    const u16* __restrict__ A, const u16* __restrict__ B,
    const float* __restrict__ bias, float* __restrict__ outf, int n_nodes)
{
    constexpr int NT = 8;
    __shared__ uint4 smem[3072];          // 48 KB: A_lds[0..1024) | B_lds[1024..3072)
    uint4* A_lds = smem;
    uint4* B_lds = smem + 1024;

    const int t = threadIdx.x;
    const int node0 = blockIdx.x * 64;
    const int cbase = blockIdx.y * 128;   // column-half offset

#pragma unroll
    for (int i = 0; i < 4; ++i) {
        int gl = t + 256 * i;
        int r = gl >> 4, g = gl & 15;
        uint4 v = make_uint4(0u, 0u, 0u, 0u);
        int node = node0 + r;
        if (node < n_nodes) v = *(const uint4*)(A + (size_t)node * 128 + g * 8);
        A_lds[r * 16 + (g ^ (r & 7))] = v;
    }
#pragma unroll
    for (int i = 0; i < 8; ++i) {
        int gl = t + 256 * i;
        int r = gl >> 4, g = gl & 15;
        B_lds[r * 16 + (g ^ (r & 7))] = *(const uint4*)(B + (size_t)(cbase + r) * 128 + g * 8);
    }

    const int w  = t >> 6;
    const int l  = t & 63;
    const int lm = l & 15;
    const int lg = l >> 4;
    const int arow = w * 16 + lm;
    const int asw  = arow & 7;

    f32x4 acc[NT];
#pragma unroll
    for (int n = 0; n < NT; ++n) acc[n] = f32x4{0.f, 0.f, 0.f, 0.f};

    __syncthreads();
#pragma unroll
    for (int ks = 0; ks < 4; ++ks) {
        int ag = lg + ks * 4;
        bf16x8 af = __builtin_bit_cast(bf16x8, A_lds[arow * 16 + (ag ^ asw)]);
#pragma unroll
        for (int n = 0; n < NT; ++n) {
            int brow = n * 16 + lm;
            bf16x8 bf = __builtin_bit_cast(bf16x8, B_lds[brow * 16 + (ag ^ (brow & 7))]);
            acc[n] = __builtin_amdgcn_mfma_f32_16x16x32_bf16(af, bf, acc[n], 0, 0, 0);
        }
    }

    // epilogue: stage per-wave 16x128 into LDS (2 chunks of 8 rows), stride 132
    float bc[NT];
#pragma unroll
    for (int n = 0; n < NT; ++n) {
        int c = cbase + n * 16 + lm;
        bc[n] = (c < NCLS) ? bias[c] : 0.f;
    }
    float* S = reinterpret_cast<float*>(smem);   // 4 waves x 8 rows x 132 = 16.9 KB
    __syncthreads();
#pragma unroll
    for (int rc = 0; rc < 2; ++rc) {
        if (rc) __syncthreads();
        if ((lg >> 1) == rc) {
            int lrow = (lg & 1) * 4;
            float* Sw = S + ((size_t)w * 8 + lrow) * 132;
#pragma unroll
            for (int n = 0; n < NT; ++n) {
#pragma unroll
                for (int r = 0; r < 4; ++r) {
                    Sw[r * 132 + n * 16 + lm] = acc[n][r] + bc[n];
                }
            }
        }
        __syncthreads();
        const float* Sw = S + (size_t)w * 8 * 132;
#pragma unroll
        for (int row8 = 0; row8 < 8; ++row8) {
            int node = node0 + w * 16 + rc * 8 + row8;   // wave-uniform
            if (node >= n_nodes) continue;
            float* orow = outf + (size_t)node * NCLS + cbase;
#pragma unroll
            for (int k = 0; k < 2; ++k) {
                int c = k * 64 + l;
                if (cbase + c < NCLS) orow[c] = Sw[row8 * 132 + c];
            }
        }
    }
}

extern "C" void kernel_launch(void* const* d_in, const int* in_sizes, int n_in,
                              void* d_out, int out_size, void* d_ws, size_t ws_size,
                              hipStream_t stream) {
    const float* x   = (const float*)d_in[0];
    const int*   ei  = (const int*)d_in[1];
    const float* W1l = (const float*)d_in[2];
    const float* b1  = (const float*)d_in[3];
    const float* W1r = (const float*)d_in[4];
    const float* W2l = (const float*)d_in[5];
    const float* b2  = (const float*)d_in[6];
    const float* W2r = (const float*)d_in[7];
    float* out = (float*)d_out;

    const int N = in_sizes[0] / DIM;     // 100000  (< 2^17, required by packing)
    const int E = in_sizes[1] / 2;       // 1600000
    const int NPAD = ((N + 63) / 64) * 64;
    const int NXP = (N + PSIZE - 1) / PSIZE;          // 391 partitions
    const int NSC = NXP * NCHUNK;                     // 75072 scan entries
    const int NB2 = (NSC + SCAN_CHUNK - 1) / SCAN_CHUNK;   // 74 (<=256 required)

    // workspace layout
    char* wp = (char*)d_ws;
    u16* A1 = (u16*)wp;                 wp += (size_t)NPAD * 128 * 2;
    u16* A2 = (u16*)wp;                 wp += (size_t)NPAD * 128 * 2;
    u16* B1 = (u16*)wp;                 wp += 64 * 128 * 2;
    u16* B2 = (u16*)wp;                 wp += 256 * 128 * 2;
    int* bcnt = (int*)wp;               wp += (size_t)NSC * 4;
    int* boff = (int*)wp;               wp += (size_t)(NSC + 1) * 4;
    int* bsum = (int*)wp;               wp += 1024 * 4;
    int* row_ptr = (int*)wp;            wp += (size_t)(N + 1) * 4;
    u32* bucket = (u32*)wp;             wp += (size_t)E * 4;
    int* nbr = (int*)wp;                wp += (size_t)E * 4;

    const int chunk_size = (E + NCHUNK - 1) / NCHUNK;
    const int nx8 = N * 8;
    const int prep_items = nx8 + 64 * 128 + 256 * 128;
    const int prep_blocks = (prep_items + 255) / 256;

    // ---- fused histogram + prep ----
    build_kernel<<<NCHUNK + prep_blocks, 256, 0, stream>>>(
        ei + E, E, chunk_size, NXP, bcnt, x, A1, nx8, W1l, W1r, B1, W2l, W2r, B2);

    // ---- 2-launch scan ----
    scan_block_sums<<<NB2, 256, 0, stream>>>(bcnt, NSC, bsum);
    scan_final_boff<<<NB2, 256, 0, stream>>>(bcnt, NSC, bsum, NB2, boff, E);

    // ---- scatter + per-partition counting sort ----
    bucket_scatter<<<NCHUNK, 256, 0, stream>>>(ei, E, chunk_size, NXP, boff, bucket);
    sort_bucket<<<NXP, 256, 0, stream>>>(bucket, boff, nbr, row_ptr, N, E);

    const int gemm_blocks = NPAD / 64;

    // ---- layer 1 (pull at full occupancy, then GEMM) ----
    pull_bf16<<<(nx8 + 255) / 256, 256, 0, stream>>>(A1, row_ptr, nbr, A1, N);
    gemm1_kernel<<<gemm_blocks, 256, 0, stream>>>(A1, B1, b1, A2, N);

    // ---- layer 2 (pull, then split-N GEMM) ----
    pull_bf16<<<(nx8 + 255) / 256, 256, 0, stream>>>(A2, row_ptr, nbr, A2, N);
    gemm2_kernel<<<dim3(gemm_blocks, 2), 256, 0, stream>>>(A2, B2, b2, out, N);
}